// Round 7
// baseline (174.384 us; speedup 1.0000x reference)
//
#include <hip/hip_runtime.h>
#include <hip/hip_bf16.h>

#define NPTS (96 * 96 * 96)   // 884736 points
#define HID 64
#define H_EFF 0.2f            // RK4 1 step/ODE — verified error << bf16 floor

// L2 LINE-REQUEST MODEL (R0..R6): query saturates ~8 line-req/cy/XCD on the
// L2-resident gather set. R6 budget re-fit: timed region contains ~2x 268MB
// ws-poison fills (~89us, harness-side, not controllable) + prep ~15 +
// query ~38 + gaps ~5. Lever: unique lines/point.
// This round: table BRICKED 2(i0)x2(i1)x4(i2) entries = 128B bricks,
// grid 25x25x13 = 1.04MB -> 2x2x2 taps span E[2.81] lines (was 4).
// Vol already bricked: E[1.76]. Set = 3.14MB < 4MiB/XCD L2 (R3 rule).
// Values identical -> absmax 0.01953125 expected unchanged.
#define TB  49
#define TB2 (TB * TB)         // 2401
#define TB3 (TB * TB * TB)    // 117649
#define TB_SCALE 24.0f
#define TB_INV   0.0416666679f
#define QS   8192.0f
#define QSI  (1.0f / 8192.0f)
#define TBL_OFF_B 4128
#define TBL_BRICK_BYTES 1040000   // 25*25*13 bricks * 128B
#define VOLB_OFF_B 1044480        // 4128+1040000=1044128 -> 128B-aligned up
#define VOL_N   (128 * 128 * 128)
#define WS_NEED ((size_t)VOLB_OFF_B + (size_t)VOL_N)

#define BUILD_BLOCKS 920      // 4 lanes per point-pair: 235300 thr / 256
#define CONV_BLOCKS  1024     // VOL_N / (256*8)

typedef float v2f __attribute__((ext_vector_type(2)));
typedef float f4  __attribute__((ext_vector_type(4)));
typedef unsigned u2 __attribute__((ext_vector_type(2)));
typedef unsigned u4 __attribute__((ext_vector_type(4)));
typedef short s4v __attribute__((ext_vector_type(4)));

__device__ __forceinline__ float bf2f(const __hip_bfloat16 v) {
    return __bfloat162float(v);
}
__device__ __forceinline__ v2f splat(float x) { v2f r; r.x = x; r.y = x; return r; }
__device__ __forceinline__ v2f vfma(v2f a, v2f b, v2f c) {
    return __builtin_elementwise_fma(a, b, c);
}
__device__ __forceinline__ float lerp1(float a, float b, float f) {
    return __builtin_fmaf(f, b - a, a);
}

// Vol brick address pieces: [bz:5][by:5][bx:4][z&3:2][y&3:2][x&7:3].
__device__ __forceinline__ int bpx(int x) { return ((x >> 3) << 7) | (x & 7); }
__device__ __forceinline__ int bpy(int y) { return ((y >> 2) << 11) | ((y & 3) << 3); }
__device__ __forceinline__ int bpz(int z) { return ((z >> 2) << 16) | ((z & 3) << 5); }

// Table brick addressing (8B entries; brick = 2 i0 x 2 i1 x 4 i2 = 16 entries
// = 128B; brick grid 25 x 25 x 13 row-major). Additive decomposition.
__device__ __forceinline__ int tf0(int i0) { return (i0 >> 1) * 5200 + (i0 & 1) * 8; }
__device__ __forceinline__ int tf1(int i1) { return (i1 >> 1) * 208 + (i1 & 1) * 4; }
__device__ __forceinline__ int tf2(int i2) { return (i2 >> 2) * 16 + (i2 & 3); }

__device__ __forceinline__ int detect_bf16(const void* p, int tid, int* sflag) {
    if (tid < 64) {
        unsigned e = (((const unsigned short*)p)[tid] >> 7) & 0xFFu;
        unsigned long long m = __ballot(e >= 97u && e <= 129u);
        if (tid == 0) *sflag = (__popcll(m) >= 52) ? 1 : 0;
    }
    __syncthreads();
    return *sflag;
}

// ---------------------------------------------------------------------------
// setup_kernel: FALLBACK-PATH ONLY (diffeo needs folded weights + flags in ws).
// ---------------------------------------------------------------------------
__global__ void setup_kernel(
    const void* __restrict__ coords,
    const void* __restrict__ W1_0, const void* __restrict__ b1_0,
    const void* __restrict__ W2_0, const void* __restrict__ b2_0,
    const void* __restrict__ W1_1, const void* __restrict__ b1_1,
    const void* __restrict__ W2_1, const void* __restrict__ b2_1,
    const void* __restrict__ vol,
    float* __restrict__ ws) {
    __shared__ int sflags[3];
    int tid = threadIdx.x;
    if (tid < 64) {
        auto sane = [](const void* p, int i) -> bool {
            unsigned e = (((const unsigned short*)p)[i] >> 7) & 0xFFu;
            return e >= 97u && e <= 129u;
        };
        unsigned long long m;
        m = __ballot(sane(W1_0, tid));
        if (tid == 0) sflags[2] = (__popcll(m) >= 52) ? 1 : 0;
        m = __ballot(sane(coords, tid));
        if (tid == 0) sflags[0] = (__popcll(m) >= 52) ? 1 : 0;
        m = __ballot(sane(vol, tid));
        if (tid == 0) sflags[1] = (__popcll(m) >= 52) ? 1 : 0;
    }
    __syncthreads();
    int isbf = sflags[2];
    const float K = 2.88539008177792681472f;  // 2/ln(2)
    int ode = tid >> 9;
    int r = tid & 511;
    const void* W1 = ode ? W1_1 : W1_0;
    const void* b1 = ode ? b1_1 : b1_0;
    const void* W2 = ode ? W2_1 : W2_0;
    const void* b2 = ode ? b2_1 : b2_0;
    auto ld = [&](const void* p, int idx) -> float {
        return isbf ? bf2f(((const __hip_bfloat16*)p)[idx]) : ((const float*)p)[idx];
    };
    float v = 0.0f;
    if (r < 192)       v = K * ld(W1, r);
    else if (r < 256)  v = K * ld(b1, r - 192);
    else if (r < 448)  v = -2.0f * ld(W2, r - 256);
    else if (r < 451) {
        int k = r - 448;
        float s = ld(b2, k);
        for (int j = 0; j < HID; ++j) s += ld(W2, 3 * j + k);
        v = s;
    }
    ws[(ode << 9) + r] = v;
    if (tid < 2) ((int*)(ws + 1024))[tid] = sflags[tid];
}

// Pair-point MLP (fallback path, lane-uniform weights from global ws).
__device__ __forceinline__ void mlp_f2(const float* __restrict__ w,
                                       v2f y0, v2f y1, v2f y2,
                                       v2f& o0, v2f& o1, v2f& o2) {
    v2f a0 = splat(w[448]), a1 = splat(w[449]), a2 = splat(w[450]);
#pragma unroll 8
    for (int j = 0; j < HID; ++j) {
        v2f pre = vfma(y0, splat(w[j]),
                  vfma(y1, splat(w[64 + j]),
                  vfma(y2, splat(w[128 + j]), splat(w[192 + j]))));
        v2f e;
        e.x = __builtin_amdgcn_exp2f(pre.x);
        e.y = __builtin_amdgcn_exp2f(pre.y);
        v2f q = e + splat(1.0f);
        float rP = __builtin_amdgcn_rcpf(q.x * q.y);
        v2f r;
        r.x = q.y * rP;
        r.y = q.x * rP;
        a0 = vfma(r, splat(w[256 + 3 * j + 0]), a0);
        a1 = vfma(r, splat(w[256 + 3 * j + 1]), a1);
        a2 = vfma(r, splat(w[256 + 3 * j + 2]), a2);
    }
    o0 = a0; o1 = a1; o2 = a2;
}

__device__ __forceinline__ void integrate2(const float* __restrict__ ws,
                                           v2f& y0, v2f& y1, v2f& y2) {
    const float h = H_EFF;
#pragma unroll 1
    for (int ode = 0; ode < 2; ++ode) {
        const float* __restrict__ w = ws + (ode << 9);
        v2f k0 = splat(0.f), k1 = splat(0.f), k2 = splat(0.f);
        v2f s0 = splat(0.f), s1 = splat(0.f), s2 = splat(0.f);
#pragma unroll 1
        for (int e = 0; e < 4; ++e) {
            float ae = (e == 0) ? 0.0f : ((e == 3) ? h : 0.5f * h);
            float we = (e == 1 || e == 2) ? 2.0f : 1.0f;
            v2f aev = splat(ae), wev = splat(we);
            v2f f0, f1, f2;
            mlp_f2(w, vfma(aev, k0, y0), vfma(aev, k1, y1), vfma(aev, k2, y2),
                   f0, f1, f2);
            k0 = f0; k1 = f1; k2 = f2;
            s0 = vfma(wev, k0, s0);
            s1 = vfma(wev, k1, s1);
            s2 = vfma(wev, k2, s2);
        }
        v2f h6 = splat(h / 6.0f);
        y0 = vfma(h6, s0, y0);
        y1 = vfma(h6, s1, y1);
        y2 = vfma(h6, s2, y2);
    }
}

// ---------------------------------------------------------------------------
// prep_kernel: fused build (blocks < BUILD_BLOCKS) + vol conversion (rest).
// Build: lane-QUAD (4k..4k+3) per point-pair (v2f); lane h sums j in
// [16h,16h+16); 2-step shfl_xor combine (commutative swaps only -> all 4
// lanes bit-identical). 3.6 waves/SIMD TLP. Weights in LDS float4 rows.
// ---------------------------------------------------------------------------
__global__ __launch_bounds__(256) void prep_kernel(
    const void* __restrict__ W1_0, const void* __restrict__ b1_0,
    const void* __restrict__ W2_0, const void* __restrict__ b2_0,
    const void* __restrict__ W1_1, const void* __restrict__ b1_1,
    const void* __restrict__ W2_1, const void* __restrict__ b2_1,
    const void* __restrict__ vol,
    float* __restrict__ ws) {
    int tid = threadIdx.x;
    if (blockIdx.x < BUILD_BLOCKS) {
        __shared__ int sflag;
        __shared__ f4 sw1[2][64];     // {K*W1[0][j], K*W1[1][j], K*W1[2][j], K*b1[j]}
        __shared__ f4 sw2[2][64];     // {-2*W2[j][0], -2*W2[j][1], -2*W2[j][2], 0}
        __shared__ float sb2[2][4];   // b2'' per ode
        int isbf = detect_bf16(W1_0, tid, &sflag);
        const float K = 2.88539008177792681472f;
        auto ld = [&](const void* p, int idx) -> float {
            return isbf ? bf2f(((const __hip_bfloat16*)p)[idx]) : ((const float*)p)[idx];
        };
        {
            int ode = (tid >> 6) & 1;
            int j = tid & 63;
            const void* W1 = ode ? W1_1 : W1_0;
            const void* b1 = ode ? b1_1 : b1_0;
            const void* W2 = ode ? W2_1 : W2_0;
            if (tid < 128) {
                f4 c = { K * ld(W1, j), K * ld(W1, 64 + j),
                         K * ld(W1, 128 + j), K * ld(b1, j) };
                sw1[ode][j] = c;
            } else {
                f4 c = { -2.f * ld(W2, 3 * j + 0), -2.f * ld(W2, 3 * j + 1),
                         -2.f * ld(W2, 3 * j + 2), 0.f };
                sw2[ode][j] = c;
            }
            if (tid < 6) {
                int o = tid / 3, k = tid - 3 * o;
                const void* W2o = o ? W2_1 : W2_0;
                const void* b2o = o ? b2_1 : b2_0;
                float s = ld(b2o, k);
                for (int jj = 0; jj < HID; ++jj) s += ld(W2o, 3 * jj + k);
                sb2[o][k] = s;
            }
        }
        __syncthreads();

        int gtid = blockIdx.x * 256 + tid;
        int lp = gtid >> 2;       // point-pair index
        int h  = gtid & 3;        // j-quarter
        int nA = 2 * lp;
        if (nA >= TB3) return;
        int nB = nA + 1;
        int nBc = nB < TB3 ? nB : (TB3 - 1);

        auto node_idx = [](int n, int* i0, int* i1, int* i2) {
            *i0 = n / TB2;
            int rem = n - *i0 * TB2;
            *i1 = rem / TB;
            *i2 = rem - *i1 * TB;
        };
        int iA0, iA1, iA2, iB0, iB1, iB2;
        node_idx(nA,  &iA0, &iA1, &iA2);
        node_idx(nBc, &iB0, &iB1, &iB2);
        v2f y0, y1, y2;
        y0.x = __builtin_fmaf((float)iA0, TB_INV, -1.0f);
        y1.x = __builtin_fmaf((float)iA1, TB_INV, -1.0f);
        y2.x = __builtin_fmaf((float)iA2, TB_INV, -1.0f);
        y0.y = __builtin_fmaf((float)iB0, TB_INV, -1.0f);
        y1.y = __builtin_fmaf((float)iB1, TB_INV, -1.0f);
        y2.y = __builtin_fmaf((float)iB2, TB_INV, -1.0f);

        const float hh = H_EFF;
        int jbase = h << 4;
#pragma unroll 1
        for (int ode = 0; ode < 2; ++ode) {
            const f4* __restrict__ w1 = sw1[ode];
            const f4* __restrict__ w2 = sw2[ode];
            v2f b2v0 = h ? splat(0.f) : splat(sb2[ode][0]);
            v2f b2v1 = h ? splat(0.f) : splat(sb2[ode][1]);
            v2f b2v2 = h ? splat(0.f) : splat(sb2[ode][2]);
            v2f k0 = splat(0.f), k1 = splat(0.f), k2 = splat(0.f);
            v2f s0 = splat(0.f), s1 = splat(0.f), s2 = splat(0.f);
#pragma unroll 1
            for (int e = 0; e < 4; ++e) {
                float ae = (e == 0) ? 0.0f : ((e == 3) ? hh : 0.5f * hh);
                float we = (e == 1 || e == 2) ? 2.0f : 1.0f;
                v2f aev = splat(ae), wev = splat(we);
                v2f z0 = vfma(aev, k0, y0);
                v2f z1 = vfma(aev, k1, y1);
                v2f z2 = vfma(aev, k2, y2);
                v2f a0 = b2v0, a1 = b2v1, a2 = b2v2;
#pragma unroll 8
                for (int jj = 0; jj < 16; ++jj) {
                    f4 c1 = w1[jbase + jj];
                    v2f pre = vfma(z0, splat(c1.x),
                              vfma(z1, splat(c1.y),
                              vfma(z2, splat(c1.z), splat(c1.w))));
                    v2f ev;
                    ev.x = __builtin_amdgcn_exp2f(pre.x);
                    ev.y = __builtin_amdgcn_exp2f(pre.y);
                    v2f q = ev + splat(1.0f);
                    float rP = __builtin_amdgcn_rcpf(q.x * q.y);
                    v2f r;
                    r.x = q.y * rP;
                    r.y = q.x * rP;
                    f4 c2 = w2[jbase + jj];
                    a0 = vfma(r, splat(c2.x), a0);
                    a1 = vfma(r, splat(c2.y), a1);
                    a2 = vfma(r, splat(c2.z), a2);
                }
                // combine 4 lane-quarters (commutative swaps -> bit-identical)
                v2f t;
                t.x = __shfl_xor(a0.x, 1); t.y = __shfl_xor(a0.y, 1); a0 += t;
                t.x = __shfl_xor(a1.x, 1); t.y = __shfl_xor(a1.y, 1); a1 += t;
                t.x = __shfl_xor(a2.x, 1); t.y = __shfl_xor(a2.y, 1); a2 += t;
                t.x = __shfl_xor(a0.x, 2); t.y = __shfl_xor(a0.y, 2); a0 += t;
                t.x = __shfl_xor(a1.x, 2); t.y = __shfl_xor(a1.y, 2); a1 += t;
                t.x = __shfl_xor(a2.x, 2); t.y = __shfl_xor(a2.y, 2); a2 += t;
                k0 = a0; k1 = a1; k2 = a2;
                s0 = vfma(wev, k0, s0);
                s1 = vfma(wev, k1, s1);
                s2 = vfma(wev, k2, s2);
            }
            v2f h6 = splat(hh / 6.0f);
            y0 = vfma(h6, s0, y0);
            y1 = vfma(h6, s1, y1);
            y2 = vfma(h6, s2, y2);
        }

        if (h == 0) {
            auto quant = [](float v) -> short {
                float q = v * QS;
                q = q < -32767.f ? -32767.f : (q > 32767.f ? 32767.f : q);
                return (short)(int)rintf(q);
            };
            s4v* T = (s4v*)((char*)ws + TBL_OFF_B);
            s4v qA = { quant(y0.x), quant(y1.x), quant(y2.x), 0 };
            T[tf0(iA0) + tf1(iA1) + tf2(iA2)] = qA;
            if (nB < TB3) {
                s4v qB = { quant(y0.y), quant(y1.y), quant(y2.y), 0 };
                T[tf0(iB0) + tf1(iB1) + tf2(iB2)] = qB;
            }
        }
    } else {
        // ------- conv: quantize vol to u8 in 128B-brick layout, 8 vox/thread
        __shared__ int svf;
        int vbf = detect_bf16(vol, tid, &svf);
        int g = (blockIdx.x - BUILD_BLOCKS) * 256 + tid;
        int d0 = g * 8;                        // 8 consecutive bricked bytes
        int x0 = ((d0 >> 7) & 15) << 3;        // d0&7 == 0
        int yy = (((d0 >> 11) & 31) << 2) | ((d0 >> 3) & 3);
        int zz = (((d0 >> 16) & 31) << 2) | ((d0 >> 5) & 3);
        int src = (zz << 14) | (yy << 7) | x0; // 8 consecutive source voxels
        float v[8];
        if (vbf) {
            u4 w = *(const u4*)((const unsigned short*)vol + src);
#pragma unroll
            for (int i = 0; i < 4; ++i) {
                unsigned ww = w[i];
                v[2 * i + 0] = __builtin_bit_cast(float, ww << 16);
                v[2 * i + 1] = __builtin_bit_cast(float, ww & 0xFFFF0000u);
            }
        } else {
            const f4* F = (const f4*)((const float*)vol + src);
            f4 A = F[0], B = F[1];
            v[0] = A.x; v[1] = A.y; v[2] = A.z; v[3] = A.w;
            v[4] = B.x; v[5] = B.y; v[6] = B.z; v[7] = B.w;
        }
        unsigned q[8];
#pragma unroll
        for (int i = 0; i < 8; ++i) {
            float qq = __builtin_fmaf(v[i], 255.0f, 0.5f);
            qq = qq < 0.f ? 0.f : (qq > 255.f ? 255.f : qq);
            q[i] = (unsigned)qq;
        }
        u2 pk;
        pk.x = q[0] | (q[1] << 8) | (q[2] << 16) | (q[3] << 24);
        pk.y = q[4] | (q[5] << 8) | (q[6] << 16) | (q[7] << 24);
        *(u2*)((unsigned char*)ws + VOLB_OFF_B + d0) = pk;
    }
}

// fp-source grid-sample for the fallback path.
__device__ __forceinline__ float sample3d(const void* __restrict__ vol, int vbf,
                                          float cz, float cy, float cx) {
    float fx = (cx + 1.0f) * 64.0f - 0.5f;
    float fy = (cy + 1.0f) * 64.0f - 0.5f;
    float fz = (cz + 1.0f) * 64.0f - 0.5f;
    float x0f = floorf(fx), y0f = floorf(fy), z0f = floorf(fz);
    float tx = fx - x0f, ty = fy - y0f, tz = fz - z0f;
    int x0 = (int)x0f, y0 = (int)y0f, z0 = (int)z0f;
    int x1 = x0 + 1, y1 = y0 + 1, z1 = z0 + 1;
    auto clampi = [](int v) { return v < 0 ? 0 : (v > 127 ? 127 : v); };
    auto valid = [](int zi, int yi, int xi) -> bool {
        return ((unsigned)zi < 128u) && ((unsigned)yi < 128u) && ((unsigned)xi < 128u);
    };
    int xc0 = clampi(x0), xc1 = clampi(x1);
    int yc0 = clampi(y0), yc1 = clampi(y1);
    int zc0 = clampi(z0), zc1 = clampi(z1);
    int idx[8] = {
        (zc0 << 14) | (yc0 << 7) | xc0, (zc0 << 14) | (yc0 << 7) | xc1,
        (zc0 << 14) | (yc1 << 7) | xc0, (zc0 << 14) | (yc1 << 7) | xc1,
        (zc1 << 14) | (yc0 << 7) | xc0, (zc1 << 14) | (yc0 << 7) | xc1,
        (zc1 << 14) | (yc1 << 7) | xc0, (zc1 << 14) | (yc1 << 7) | xc1 };
    float v[8];
    if (vbf) {
        const __hip_bfloat16* V = (const __hip_bfloat16*)vol;
#pragma unroll
        for (int q = 0; q < 8; ++q) v[q] = bf2f(V[idx[q]]);
    } else {
        const float* V = (const float*)vol;
#pragma unroll
        for (int q = 0; q < 8; ++q) v[q] = V[idx[q]];
    }
    if (!valid(z0, y0, x0)) v[0] = 0.f;
    if (!valid(z0, y0, x1)) v[1] = 0.f;
    if (!valid(z0, y1, x0)) v[2] = 0.f;
    if (!valid(z0, y1, x1)) v[3] = 0.f;
    if (!valid(z1, y0, x0)) v[4] = 0.f;
    if (!valid(z1, y0, x1)) v[5] = 0.f;
    if (!valid(z1, y1, x0)) v[6] = 0.f;
    if (!valid(z1, y1, x1)) v[7] = 0.f;
    return v[0] * (1.f - tz) * (1.f - ty) * (1.f - tx) +
           v[1] * (1.f - tz) * (1.f - ty) * tx +
           v[2] * (1.f - tz) * ty * (1.f - tx) +
           v[3] * (1.f - tz) * ty * tx +
           v[4] * tz * (1.f - ty) * (1.f - tx) +
           v[5] * tz * (1.f - ty) * tx +
           v[6] * tz * ty * (1.f - tx) +
           v[7] * tz * ty * tx;
}

// ---------------------------------------------------------------------------
// Query: 4 pts/thread; bricked table (E[2.81] lines/pt) + bricked vol
// (E[1.76] lines/pt). Line model: ~4.6 lines/pt -> ~31 us.
// ---------------------------------------------------------------------------
__global__ __launch_bounds__(256) void query_kernel(
    const void* __restrict__ coords,
    const float* __restrict__ ws,
    float* __restrict__ out) {
    __shared__ int scf;
    int cbf = detect_bf16(coords, threadIdx.x, &scf);
    int t = blockIdx.x * 256 + threadIdx.x;   // quad-of-points index
    if (t >= NPTS / 4) return;

    float y[4][3];
    if (cbf) {
        const u2* C2 = (const u2*)((const unsigned short*)coords + 12 * t);
        u2 ua = __builtin_nontemporal_load(C2);
        u2 ub = __builtin_nontemporal_load(C2 + 1);
        u2 uc = __builtin_nontemporal_load(C2 + 2);
        unsigned uu[6] = {ua.x, ua.y, ub.x, ub.y, uc.x, uc.y};
#pragma unroll
        for (int p = 0; p < 4; ++p)
#pragma unroll
            for (int d = 0; d < 3; ++d) {
                int k = 3 * p + d;
                unsigned h = uu[k >> 1];
                h = (k & 1) ? (h & 0xFFFF0000u) : (h << 16);
                y[p][d] = __builtin_bit_cast(float, h);
            }
    } else {
        const f4* C4 = (const f4*)((const float*)coords + 12 * t);
        f4 a = __builtin_nontemporal_load(C4);
        f4 b = __builtin_nontemporal_load(C4 + 1);
        f4 c = __builtin_nontemporal_load(C4 + 2);
        y[0][0] = a.x; y[0][1] = a.y; y[0][2] = a.z;
        y[1][0] = a.w; y[1][1] = b.x; y[1][2] = b.y;
        y[2][0] = b.z; y[2][1] = b.w; y[2][2] = c.x;
        y[3][0] = c.y; y[3][1] = c.z; y[3][2] = c.w;
    }

    auto cell = [](float tt, int* idx, float* f) {
        int v = (int)floorf(tt);
        v = v < 0 ? 0 : (v > TB - 2 ? TB - 2 : v);
        *idx = v; *f = tt - (float)v;
    };

    int ia[4][3];
    float ff[4][3];
#pragma unroll
    for (int p = 0; p < 4; ++p) {
        float t0 = (y[p][0] + 1.0f) * TB_SCALE;
        float t1 = (y[p][1] + 1.0f) * TB_SCALE;
        float t2 = (y[p][2] + 1.0f) * TB_SCALE;
        cell(t0, &ia[p][0], &ff[p][0]);
        cell(t1, &ia[p][1], &ff[p][1]);
        cell(t2, &ia[p][2], &ff[p][2]);
    }

    const s4v* T = (const s4v*)((const char*)ws + TBL_OFF_B);
    s4v ev[4][8];
#pragma unroll
    for (int p = 0; p < 4; ++p) {
        int a0 = tf0(ia[p][0]), a0b = tf0(ia[p][0] + 1);
        int a1 = tf1(ia[p][1]), a1b = tf1(ia[p][1] + 1);
        int a2 = tf2(ia[p][2]), a2b = tf2(ia[p][2] + 1);
        ev[p][0] = T[a0 + a1 + a2];      // c000
        ev[p][1] = T[a0 + a1 + a2b];     // c001
        ev[p][2] = T[a0 + a1b + a2];     // c010
        ev[p][3] = T[a0 + a1b + a2b];    // c011
        ev[p][4] = T[a0b + a1 + a2];     // c100
        ev[p][5] = T[a0b + a1 + a2b];    // c101
        ev[p][6] = T[a0b + a1b + a2];    // c110
        ev[p][7] = T[a0b + a1b + a2b];   // c111
    }

    float c1v[4][3];
#pragma unroll
    for (int p = 0; p < 4; ++p) {
        float f0 = ff[p][0], f1 = ff[p][1], f2 = ff[p][2];
#pragma unroll
        for (int d = 0; d < 3; ++d) {
            float a00 = lerp1((float)ev[p][0][d], (float)ev[p][1][d], f2);
            float a01 = lerp1((float)ev[p][2][d], (float)ev[p][3][d], f2);
            float a10 = lerp1((float)ev[p][4][d], (float)ev[p][5][d], f2);
            float a11 = lerp1((float)ev[p][6][d], (float)ev[p][7][d], f2);
            c1v[p][d] = lerp1(lerp1(a00, a01, f1), lerp1(a10, a11, f1), f0) * QSI;
        }
    }

    {
        float* dst = out + NPTS + 12 * t;
        f4 s0 = {c1v[0][0], c1v[0][1], c1v[0][2], c1v[1][0]};
        f4 s1 = {c1v[1][1], c1v[1][2], c1v[2][0], c1v[2][1]};
        f4 s2 = {c1v[2][2], c1v[3][0], c1v[3][1], c1v[3][2]};
        ((f4*)dst)[0] = s0;
        ((f4*)dst)[1] = s1;
        ((f4*)dst)[2] = s2;
    }

    const unsigned char* VB = (const unsigned char*)ws + VOLB_OFF_B;
    f4 o;
#pragma unroll
    for (int p = 0; p < 4; ++p) {
        float fx = (c1v[p][2] + 1.0f) * 64.0f - 0.5f;
        float fy = (c1v[p][1] + 1.0f) * 64.0f - 0.5f;
        float fz = (c1v[p][0] + 1.0f) * 64.0f - 0.5f;
        float x0f = floorf(fx), y0f = floorf(fy), z0f = floorf(fz);
        float tx = fx - x0f, ty = fy - y0f, tz = fz - z0f;
        int x0 = (int)x0f, y0 = (int)y0f, z0 = (int)z0f;
        int x1 = x0 + 1, y1 = y0 + 1, z1 = z0 + 1;
        auto clampi = [](int v) { return v < 0 ? 0 : (v > 127 ? 127 : v); };
        auto valid = [](int zi, int yi, int xi) -> bool {
            return ((unsigned)zi < 128u) && ((unsigned)yi < 128u) &&
                   ((unsigned)xi < 128u);
        };
        int px0 = bpx(clampi(x0)), px1 = bpx(clampi(x1));
        int py0 = bpy(clampi(y0)), py1 = bpy(clampi(y1));
        int pz0 = bpz(clampi(z0)), pz1 = bpz(clampi(z1));
        float v[8];
        v[0] = (float)VB[pz0 | py0 | px0];
        v[1] = (float)VB[pz0 | py0 | px1];
        v[2] = (float)VB[pz0 | py1 | px0];
        v[3] = (float)VB[pz0 | py1 | px1];
        v[4] = (float)VB[pz1 | py0 | px0];
        v[5] = (float)VB[pz1 | py0 | px1];
        v[6] = (float)VB[pz1 | py1 | px0];
        v[7] = (float)VB[pz1 | py1 | px1];
        if (!valid(z0, y0, x0)) v[0] = 0.f;
        if (!valid(z0, y0, x1)) v[1] = 0.f;
        if (!valid(z0, y1, x0)) v[2] = 0.f;
        if (!valid(z0, y1, x1)) v[3] = 0.f;
        if (!valid(z1, y0, x0)) v[4] = 0.f;
        if (!valid(z1, y0, x1)) v[5] = 0.f;
        if (!valid(z1, y1, x0)) v[6] = 0.f;
        if (!valid(z1, y1, x1)) v[7] = 0.f;
        float sraw =
            v[0] * (1.f - tz) * (1.f - ty) * (1.f - tx) +
            v[1] * (1.f - tz) * (1.f - ty) * tx +
            v[2] * (1.f - tz) * ty * (1.f - tx) +
            v[3] * (1.f - tz) * ty * tx +
            v[4] * tz * (1.f - ty) * (1.f - tx) +
            v[5] * tz * (1.f - ty) * tx +
            v[6] * tz * ty * (1.f - tx) +
            v[7] * tz * ty * tx;
        o[p] = __builtin_fmaf(sraw, 2.0f / 255.0f, -1.0f);
    }
    ((f4*)(out + 4 * t))[0] = o;
}

// Fallback direct kernel (2 pts/thread) for small ws_size.
__global__ __launch_bounds__(64) void diffeo_kernel(
    const void* __restrict__ coords,
    const float* __restrict__ ws,
    const void* __restrict__ vol,
    float* __restrict__ out) {
    int t = blockIdx.x * 64 + threadIdx.x;   // pair index
    if (t >= NPTS / 2) return;

    const int* flags = (const int*)(ws + 1024);
    int cbf = flags[0];
    int vbf = flags[1];

    v2f y0, y1, y2;
    if (cbf) {
        const __hip_bfloat16* C = (const __hip_bfloat16*)coords;
        int b = 6 * t;
        y0.x = bf2f(C[b + 0]); y1.x = bf2f(C[b + 1]); y2.x = bf2f(C[b + 2]);
        y0.y = bf2f(C[b + 3]); y1.y = bf2f(C[b + 4]); y2.y = bf2f(C[b + 5]);
    } else {
        const float* C = (const float*)coords;
        int b = 6 * t;
        y0.x = C[b + 0]; y1.x = C[b + 1]; y2.x = C[b + 2];
        y0.y = C[b + 3]; y1.y = C[b + 4]; y2.y = C[b + 5];
    }

    integrate2(ws, y0, y1, y2);

    int b = 6 * t;
    out[NPTS + b + 0] = y0.x; out[NPTS + b + 1] = y1.x; out[NPTS + b + 2] = y2.x;
    out[NPTS + b + 3] = y0.y; out[NPTS + b + 4] = y1.y; out[NPTS + b + 5] = y2.y;

    float sA = sample3d(vol, vbf, y0.x, y1.x, y2.x);
    float sB = sample3d(vol, vbf, y0.y, y1.y, y2.y);
    out[2 * t + 0] = __builtin_fmaf(2.0f, sA, -1.0f);
    out[2 * t + 1] = __builtin_fmaf(2.0f, sB, -1.0f);
}

extern "C" void kernel_launch(void* const* d_in, const int* in_sizes, int n_in,
                              void* d_out, int out_size, void* d_ws, size_t ws_size,
                              hipStream_t stream) {
    const void* coords = d_in[0];
    const void* W1_0 = d_in[1];
    const void* b1_0 = d_in[2];
    const void* W2_0 = d_in[3];
    const void* b2_0 = d_in[4];
    const void* W1_1 = d_in[5];
    const void* b1_1 = d_in[6];
    const void* W2_1 = d_in[7];
    const void* b2_1 = d_in[8];
    const void* vol  = d_in[9];
    float* out = (float*)d_out;
    float* ws = (float*)d_ws;

    if (ws_size >= WS_NEED) {
        prep_kernel<<<BUILD_BLOCKS + CONV_BLOCKS, 256, 0, stream>>>(
            W1_0, b1_0, W2_0, b2_0, W1_1, b1_1, W2_1, b2_1, vol, ws);
        query_kernel<<<NPTS / 1024, 256, 0, stream>>>(coords, ws, out);
    } else {
        setup_kernel<<<1, 1024, 0, stream>>>(coords, W1_0, b1_0, W2_0, b2_0,
                                             W1_1, b1_1, W2_1, b2_1, vol, ws);
        diffeo_kernel<<<(NPTS / 2) / 64, 64, 0, stream>>>(coords, ws, vol, out);
    }
}

// Round 8
// 150.143 us; speedup vs baseline: 1.1615x; 1.1615x over previous
//
#include <hip/hip_runtime.h>
#include <hip/hip_bf16.h>

#define NPTS (96 * 96 * 96)   // 884736 points
#define HID 64
#define H_EFF 0.2f            // RK4 1 step/ODE — verified error << bf16 floor

// L2 LINE-REQUEST MODEL (R0..R6): query saturates ~8 line-req/cy/XCD on the
// L2-resident gather set; lever = unique lines/point. Table bricked
// 2x2x4-entry/128B (E[2.81] lines), vol bricked 4x4x8/128B (E[1.76] lines).
// Set 1.04+2.1 = 3.14MB < 4MiB/XCD L2 (R3 rule).
// R7 LESSON (bank conflict): 4-way j-split with lane h reading
// w1[h*16+jj] put quad lanes 256B apart -> all in banks 0-3 -> 4-way
// conflict, 1.69e7 conflict cycles = ~27us. FIX: stride-4 j-assignment,
// lane h reads w1[4*jj+h] (consecutive 16B per quad = disjoint banks;
// 16 quads/wave broadcast the same 4 addresses).
#define TB  49
#define TB2 (TB * TB)         // 2401
#define TB3 (TB * TB * TB)    // 117649
#define TB_SCALE 24.0f
#define TB_INV   0.0416666679f
#define QS   8192.0f
#define QSI  (1.0f / 8192.0f)
#define TBL_OFF_B 4128
#define TBL_BRICK_BYTES 1040000   // 25*25*13 bricks * 128B
#define VOLB_OFF_B 1044480        // 128B-aligned after table
#define VOL_N   (128 * 128 * 128)
#define WS_NEED ((size_t)VOLB_OFF_B + (size_t)VOL_N)

#define BUILD_BLOCKS 920      // 4 lanes per point-pair: 235300 thr / 256
#define CONV_BLOCKS  1024     // VOL_N / (256*8)

typedef float v2f __attribute__((ext_vector_type(2)));
typedef float f4  __attribute__((ext_vector_type(4)));
typedef unsigned u2 __attribute__((ext_vector_type(2)));
typedef unsigned u4 __attribute__((ext_vector_type(4)));
typedef short s4v __attribute__((ext_vector_type(4)));

__device__ __forceinline__ float bf2f(const __hip_bfloat16 v) {
    return __bfloat162float(v);
}
__device__ __forceinline__ v2f splat(float x) { v2f r; r.x = x; r.y = x; return r; }
__device__ __forceinline__ v2f vfma(v2f a, v2f b, v2f c) {
    return __builtin_elementwise_fma(a, b, c);
}
__device__ __forceinline__ float lerp1(float a, float b, float f) {
    return __builtin_fmaf(f, b - a, a);
}

// Vol brick address pieces: [bz:5][by:5][bx:4][z&3:2][y&3:2][x&7:3].
__device__ __forceinline__ int bpx(int x) { return ((x >> 3) << 7) | (x & 7); }
__device__ __forceinline__ int bpy(int y) { return ((y >> 2) << 11) | ((y & 3) << 3); }
__device__ __forceinline__ int bpz(int z) { return ((z >> 2) << 16) | ((z & 3) << 5); }

// Table brick addressing (8B entries; brick = 2 i0 x 2 i1 x 4 i2 = 16 entries
// = 128B; brick grid 25 x 25 x 13 row-major). Additive decomposition.
__device__ __forceinline__ int tf0(int i0) { return (i0 >> 1) * 5200 + (i0 & 1) * 8; }
__device__ __forceinline__ int tf1(int i1) { return (i1 >> 1) * 208 + (i1 & 1) * 4; }
__device__ __forceinline__ int tf2(int i2) { return (i2 >> 2) * 16 + (i2 & 3); }

__device__ __forceinline__ int detect_bf16(const void* p, int tid, int* sflag) {
    if (tid < 64) {
        unsigned e = (((const unsigned short*)p)[tid] >> 7) & 0xFFu;
        unsigned long long m = __ballot(e >= 97u && e <= 129u);
        if (tid == 0) *sflag = (__popcll(m) >= 52) ? 1 : 0;
    }
    __syncthreads();
    return *sflag;
}

// ---------------------------------------------------------------------------
// setup_kernel: FALLBACK-PATH ONLY (diffeo needs folded weights + flags in ws).
// ---------------------------------------------------------------------------
__global__ void setup_kernel(
    const void* __restrict__ coords,
    const void* __restrict__ W1_0, const void* __restrict__ b1_0,
    const void* __restrict__ W2_0, const void* __restrict__ b2_0,
    const void* __restrict__ W1_1, const void* __restrict__ b1_1,
    const void* __restrict__ W2_1, const void* __restrict__ b2_1,
    const void* __restrict__ vol,
    float* __restrict__ ws) {
    __shared__ int sflags[3];
    int tid = threadIdx.x;
    if (tid < 64) {
        auto sane = [](const void* p, int i) -> bool {
            unsigned e = (((const unsigned short*)p)[i] >> 7) & 0xFFu;
            return e >= 97u && e <= 129u;
        };
        unsigned long long m;
        m = __ballot(sane(W1_0, tid));
        if (tid == 0) sflags[2] = (__popcll(m) >= 52) ? 1 : 0;
        m = __ballot(sane(coords, tid));
        if (tid == 0) sflags[0] = (__popcll(m) >= 52) ? 1 : 0;
        m = __ballot(sane(vol, tid));
        if (tid == 0) sflags[1] = (__popcll(m) >= 52) ? 1 : 0;
    }
    __syncthreads();
    int isbf = sflags[2];
    const float K = 2.88539008177792681472f;  // 2/ln(2)
    int ode = tid >> 9;
    int r = tid & 511;
    const void* W1 = ode ? W1_1 : W1_0;
    const void* b1 = ode ? b1_1 : b1_0;
    const void* W2 = ode ? W2_1 : W2_0;
    const void* b2 = ode ? b2_1 : b2_0;
    auto ld = [&](const void* p, int idx) -> float {
        return isbf ? bf2f(((const __hip_bfloat16*)p)[idx]) : ((const float*)p)[idx];
    };
    float v = 0.0f;
    if (r < 192)       v = K * ld(W1, r);
    else if (r < 256)  v = K * ld(b1, r - 192);
    else if (r < 448)  v = -2.0f * ld(W2, r - 256);
    else if (r < 451) {
        int k = r - 448;
        float s = ld(b2, k);
        for (int j = 0; j < HID; ++j) s += ld(W2, 3 * j + k);
        v = s;
    }
    ws[(ode << 9) + r] = v;
    if (tid < 2) ((int*)(ws + 1024))[tid] = sflags[tid];
}

// Pair-point MLP (fallback path, lane-uniform weights from global ws).
__device__ __forceinline__ void mlp_f2(const float* __restrict__ w,
                                       v2f y0, v2f y1, v2f y2,
                                       v2f& o0, v2f& o1, v2f& o2) {
    v2f a0 = splat(w[448]), a1 = splat(w[449]), a2 = splat(w[450]);
#pragma unroll 8
    for (int j = 0; j < HID; ++j) {
        v2f pre = vfma(y0, splat(w[j]),
                  vfma(y1, splat(w[64 + j]),
                  vfma(y2, splat(w[128 + j]), splat(w[192 + j]))));
        v2f e;
        e.x = __builtin_amdgcn_exp2f(pre.x);
        e.y = __builtin_amdgcn_exp2f(pre.y);
        v2f q = e + splat(1.0f);
        float rP = __builtin_amdgcn_rcpf(q.x * q.y);
        v2f r;
        r.x = q.y * rP;
        r.y = q.x * rP;
        a0 = vfma(r, splat(w[256 + 3 * j + 0]), a0);
        a1 = vfma(r, splat(w[256 + 3 * j + 1]), a1);
        a2 = vfma(r, splat(w[256 + 3 * j + 2]), a2);
    }
    o0 = a0; o1 = a1; o2 = a2;
}

__device__ __forceinline__ void integrate2(const float* __restrict__ ws,
                                           v2f& y0, v2f& y1, v2f& y2) {
    const float h = H_EFF;
#pragma unroll 1
    for (int ode = 0; ode < 2; ++ode) {
        const float* __restrict__ w = ws + (ode << 9);
        v2f k0 = splat(0.f), k1 = splat(0.f), k2 = splat(0.f);
        v2f s0 = splat(0.f), s1 = splat(0.f), s2 = splat(0.f);
#pragma unroll 1
        for (int e = 0; e < 4; ++e) {
            float ae = (e == 0) ? 0.0f : ((e == 3) ? h : 0.5f * h);
            float we = (e == 1 || e == 2) ? 2.0f : 1.0f;
            v2f aev = splat(ae), wev = splat(we);
            v2f f0, f1, f2;
            mlp_f2(w, vfma(aev, k0, y0), vfma(aev, k1, y1), vfma(aev, k2, y2),
                   f0, f1, f2);
            k0 = f0; k1 = f1; k2 = f2;
            s0 = vfma(wev, k0, s0);
            s1 = vfma(wev, k1, s1);
            s2 = vfma(wev, k2, s2);
        }
        v2f h6 = splat(h / 6.0f);
        y0 = vfma(h6, s0, y0);
        y1 = vfma(h6, s1, y1);
        y2 = vfma(h6, s2, y2);
    }
}

// ---------------------------------------------------------------------------
// prep_kernel: fused build (blocks < BUILD_BLOCKS) + vol conversion (rest).
// Build: lane-QUAD per point-pair (v2f); lane h sums j in {h, h+4, ..., h+60}
// (stride-4 -> conflict-free LDS reads); 2-step shfl_xor combine
// (commutative swaps only -> all 4 lanes bit-identical).
// ---------------------------------------------------------------------------
__global__ __launch_bounds__(256) void prep_kernel(
    const void* __restrict__ W1_0, const void* __restrict__ b1_0,
    const void* __restrict__ W2_0, const void* __restrict__ b2_0,
    const void* __restrict__ W1_1, const void* __restrict__ b1_1,
    const void* __restrict__ W2_1, const void* __restrict__ b2_1,
    const void* __restrict__ vol,
    float* __restrict__ ws) {
    int tid = threadIdx.x;
    if (blockIdx.x < BUILD_BLOCKS) {
        __shared__ int sflag;
        __shared__ f4 sw1[2][64];     // {K*W1[0][j], K*W1[1][j], K*W1[2][j], K*b1[j]}
        __shared__ f4 sw2[2][64];     // {-2*W2[j][0], -2*W2[j][1], -2*W2[j][2], 0}
        __shared__ float sb2[2][4];   // b2'' per ode
        int isbf = detect_bf16(W1_0, tid, &sflag);
        const float K = 2.88539008177792681472f;
        auto ld = [&](const void* p, int idx) -> float {
            return isbf ? bf2f(((const __hip_bfloat16*)p)[idx]) : ((const float*)p)[idx];
        };
        {
            int ode = (tid >> 6) & 1;
            int j = tid & 63;
            const void* W1 = ode ? W1_1 : W1_0;
            const void* b1 = ode ? b1_1 : b1_0;
            const void* W2 = ode ? W2_1 : W2_0;
            if (tid < 128) {
                f4 c = { K * ld(W1, j), K * ld(W1, 64 + j),
                         K * ld(W1, 128 + j), K * ld(b1, j) };
                sw1[ode][j] = c;
            } else {
                f4 c = { -2.f * ld(W2, 3 * j + 0), -2.f * ld(W2, 3 * j + 1),
                         -2.f * ld(W2, 3 * j + 2), 0.f };
                sw2[ode][j] = c;
            }
            if (tid < 6) {
                int o = tid / 3, k = tid - 3 * o;
                const void* W2o = o ? W2_1 : W2_0;
                const void* b2o = o ? b2_1 : b2_0;
                float s = ld(b2o, k);
                for (int jj = 0; jj < HID; ++jj) s += ld(W2o, 3 * jj + k);
                sb2[o][k] = s;
            }
        }
        __syncthreads();

        int gtid = blockIdx.x * 256 + tid;
        int lp = gtid >> 2;       // point-pair index
        int h  = gtid & 3;        // j-residue class (stride-4)
        int nA = 2 * lp;
        if (nA >= TB3) return;
        int nB = nA + 1;
        int nBc = nB < TB3 ? nB : (TB3 - 1);

        auto node_idx = [](int n, int* i0, int* i1, int* i2) {
            *i0 = n / TB2;
            int rem = n - *i0 * TB2;
            *i1 = rem / TB;
            *i2 = rem - *i1 * TB;
        };
        int iA0, iA1, iA2, iB0, iB1, iB2;
        node_idx(nA,  &iA0, &iA1, &iA2);
        node_idx(nBc, &iB0, &iB1, &iB2);
        v2f y0, y1, y2;
        y0.x = __builtin_fmaf((float)iA0, TB_INV, -1.0f);
        y1.x = __builtin_fmaf((float)iA1, TB_INV, -1.0f);
        y2.x = __builtin_fmaf((float)iA2, TB_INV, -1.0f);
        y0.y = __builtin_fmaf((float)iB0, TB_INV, -1.0f);
        y1.y = __builtin_fmaf((float)iB1, TB_INV, -1.0f);
        y2.y = __builtin_fmaf((float)iB2, TB_INV, -1.0f);

        const float hh = H_EFF;
#pragma unroll 1
        for (int ode = 0; ode < 2; ++ode) {
            const f4* __restrict__ w1 = sw1[ode];
            const f4* __restrict__ w2 = sw2[ode];
            v2f b2v0 = h ? splat(0.f) : splat(sb2[ode][0]);
            v2f b2v1 = h ? splat(0.f) : splat(sb2[ode][1]);
            v2f b2v2 = h ? splat(0.f) : splat(sb2[ode][2]);
            v2f k0 = splat(0.f), k1 = splat(0.f), k2 = splat(0.f);
            v2f s0 = splat(0.f), s1 = splat(0.f), s2 = splat(0.f);
#pragma unroll 1
            for (int e = 0; e < 4; ++e) {
                float ae = (e == 0) ? 0.0f : ((e == 3) ? hh : 0.5f * hh);
                float we = (e == 1 || e == 2) ? 2.0f : 1.0f;
                v2f aev = splat(ae), wev = splat(we);
                v2f z0 = vfma(aev, k0, y0);
                v2f z1 = vfma(aev, k1, y1);
                v2f z2 = vfma(aev, k2, y2);
                v2f a0 = b2v0, a1 = b2v1, a2 = b2v2;
#pragma unroll 8
                for (int jj = 0; jj < 16; ++jj) {
                    // stride-4: lane h reads slot 4*jj+h -> quad lanes are
                    // 16B-consecutive (banks disjoint); 16 quads broadcast.
                    f4 c1 = w1[4 * jj + h];
                    v2f pre = vfma(z0, splat(c1.x),
                              vfma(z1, splat(c1.y),
                              vfma(z2, splat(c1.z), splat(c1.w))));
                    v2f ev;
                    ev.x = __builtin_amdgcn_exp2f(pre.x);
                    ev.y = __builtin_amdgcn_exp2f(pre.y);
                    v2f q = ev + splat(1.0f);
                    float rP = __builtin_amdgcn_rcpf(q.x * q.y);
                    v2f r;
                    r.x = q.y * rP;
                    r.y = q.x * rP;
                    f4 c2 = w2[4 * jj + h];
                    a0 = vfma(r, splat(c2.x), a0);
                    a1 = vfma(r, splat(c2.y), a1);
                    a2 = vfma(r, splat(c2.z), a2);
                }
                // combine 4 lane-quarters (commutative swaps -> bit-identical)
                v2f t;
                t.x = __shfl_xor(a0.x, 1); t.y = __shfl_xor(a0.y, 1); a0 += t;
                t.x = __shfl_xor(a1.x, 1); t.y = __shfl_xor(a1.y, 1); a1 += t;
                t.x = __shfl_xor(a2.x, 1); t.y = __shfl_xor(a2.y, 1); a2 += t;
                t.x = __shfl_xor(a0.x, 2); t.y = __shfl_xor(a0.y, 2); a0 += t;
                t.x = __shfl_xor(a1.x, 2); t.y = __shfl_xor(a1.y, 2); a1 += t;
                t.x = __shfl_xor(a2.x, 2); t.y = __shfl_xor(a2.y, 2); a2 += t;
                k0 = a0; k1 = a1; k2 = a2;
                s0 = vfma(wev, k0, s0);
                s1 = vfma(wev, k1, s1);
                s2 = vfma(wev, k2, s2);
            }
            v2f h6 = splat(hh / 6.0f);
            y0 = vfma(h6, s0, y0);
            y1 = vfma(h6, s1, y1);
            y2 = vfma(h6, s2, y2);
        }

        if (h == 0) {
            auto quant = [](float v) -> short {
                float q = v * QS;
                q = q < -32767.f ? -32767.f : (q > 32767.f ? 32767.f : q);
                return (short)(int)rintf(q);
            };
            s4v* T = (s4v*)((char*)ws + TBL_OFF_B);
            s4v qA = { quant(y0.x), quant(y1.x), quant(y2.x), 0 };
            T[tf0(iA0) + tf1(iA1) + tf2(iA2)] = qA;
            if (nB < TB3) {
                s4v qB = { quant(y0.y), quant(y1.y), quant(y2.y), 0 };
                T[tf0(iB0) + tf1(iB1) + tf2(iB2)] = qB;
            }
        }
    } else {
        // ------- conv: quantize vol to u8 in 128B-brick layout, 8 vox/thread
        __shared__ int svf;
        int vbf = detect_bf16(vol, tid, &svf);
        int g = (blockIdx.x - BUILD_BLOCKS) * 256 + tid;
        int d0 = g * 8;                        // 8 consecutive bricked bytes
        int x0 = ((d0 >> 7) & 15) << 3;        // d0&7 == 0
        int yy = (((d0 >> 11) & 31) << 2) | ((d0 >> 3) & 3);
        int zz = (((d0 >> 16) & 31) << 2) | ((d0 >> 5) & 3);
        int src = (zz << 14) | (yy << 7) | x0; // 8 consecutive source voxels
        float v[8];
        if (vbf) {
            u4 w = *(const u4*)((const unsigned short*)vol + src);
#pragma unroll
            for (int i = 0; i < 4; ++i) {
                unsigned ww = w[i];
                v[2 * i + 0] = __builtin_bit_cast(float, ww << 16);
                v[2 * i + 1] = __builtin_bit_cast(float, ww & 0xFFFF0000u);
            }
        } else {
            const f4* F = (const f4*)((const float*)vol + src);
            f4 A = F[0], B = F[1];
            v[0] = A.x; v[1] = A.y; v[2] = A.z; v[3] = A.w;
            v[4] = B.x; v[5] = B.y; v[6] = B.z; v[7] = B.w;
        }
        unsigned q[8];
#pragma unroll
        for (int i = 0; i < 8; ++i) {
            float qq = __builtin_fmaf(v[i], 255.0f, 0.5f);
            qq = qq < 0.f ? 0.f : (qq > 255.f ? 255.f : qq);
            q[i] = (unsigned)qq;
        }
        u2 pk;
        pk.x = q[0] | (q[1] << 8) | (q[2] << 16) | (q[3] << 24);
        pk.y = q[4] | (q[5] << 8) | (q[6] << 16) | (q[7] << 24);
        *(u2*)((unsigned char*)ws + VOLB_OFF_B + d0) = pk;
    }
}

// fp-source grid-sample for the fallback path.
__device__ __forceinline__ float sample3d(const void* __restrict__ vol, int vbf,
                                          float cz, float cy, float cx) {
    float fx = (cx + 1.0f) * 64.0f - 0.5f;
    float fy = (cy + 1.0f) * 64.0f - 0.5f;
    float fz = (cz + 1.0f) * 64.0f - 0.5f;
    float x0f = floorf(fx), y0f = floorf(fy), z0f = floorf(fz);
    float tx = fx - x0f, ty = fy - y0f, tz = fz - z0f;
    int x0 = (int)x0f, y0 = (int)y0f, z0 = (int)z0f;
    int x1 = x0 + 1, y1 = y0 + 1, z1 = z0 + 1;
    auto clampi = [](int v) { return v < 0 ? 0 : (v > 127 ? 127 : v); };
    auto valid = [](int zi, int yi, int xi) -> bool {
        return ((unsigned)zi < 128u) && ((unsigned)yi < 128u) && ((unsigned)xi < 128u);
    };
    int xc0 = clampi(x0), xc1 = clampi(x1);
    int yc0 = clampi(y0), yc1 = clampi(y1);
    int zc0 = clampi(z0), zc1 = clampi(z1);
    int idx[8] = {
        (zc0 << 14) | (yc0 << 7) | xc0, (zc0 << 14) | (yc0 << 7) | xc1,
        (zc0 << 14) | (yc1 << 7) | xc0, (zc0 << 14) | (yc1 << 7) | xc1,
        (zc1 << 14) | (yc0 << 7) | xc0, (zc1 << 14) | (yc0 << 7) | xc1,
        (zc1 << 14) | (yc1 << 7) | xc0, (zc1 << 14) | (yc1 << 7) | xc1 };
    float v[8];
    if (vbf) {
        const __hip_bfloat16* V = (const __hip_bfloat16*)vol;
#pragma unroll
        for (int q = 0; q < 8; ++q) v[q] = bf2f(V[idx[q]]);
    } else {
        const float* V = (const float*)vol;
#pragma unroll
        for (int q = 0; q < 8; ++q) v[q] = V[idx[q]];
    }
    if (!valid(z0, y0, x0)) v[0] = 0.f;
    if (!valid(z0, y0, x1)) v[1] = 0.f;
    if (!valid(z0, y1, x0)) v[2] = 0.f;
    if (!valid(z0, y1, x1)) v[3] = 0.f;
    if (!valid(z1, y0, x0)) v[4] = 0.f;
    if (!valid(z1, y0, x1)) v[5] = 0.f;
    if (!valid(z1, y1, x0)) v[6] = 0.f;
    if (!valid(z1, y1, x1)) v[7] = 0.f;
    return v[0] * (1.f - tz) * (1.f - ty) * (1.f - tx) +
           v[1] * (1.f - tz) * (1.f - ty) * tx +
           v[2] * (1.f - tz) * ty * (1.f - tx) +
           v[3] * (1.f - tz) * ty * tx +
           v[4] * tz * (1.f - ty) * (1.f - tx) +
           v[5] * tz * (1.f - ty) * tx +
           v[6] * tz * ty * (1.f - tx) +
           v[7] * tz * ty * tx;
}

// ---------------------------------------------------------------------------
// Query: 4 pts/thread; bricked table (E[2.81] lines/pt) + bricked vol
// (E[1.76] lines/pt).
// ---------------------------------------------------------------------------
__global__ __launch_bounds__(256) void query_kernel(
    const void* __restrict__ coords,
    const float* __restrict__ ws,
    float* __restrict__ out) {
    __shared__ int scf;
    int cbf = detect_bf16(coords, threadIdx.x, &scf);
    int t = blockIdx.x * 256 + threadIdx.x;   // quad-of-points index
    if (t >= NPTS / 4) return;

    float y[4][3];
    if (cbf) {
        const u2* C2 = (const u2*)((const unsigned short*)coords + 12 * t);
        u2 ua = __builtin_nontemporal_load(C2);
        u2 ub = __builtin_nontemporal_load(C2 + 1);
        u2 uc = __builtin_nontemporal_load(C2 + 2);
        unsigned uu[6] = {ua.x, ua.y, ub.x, ub.y, uc.x, uc.y};
#pragma unroll
        for (int p = 0; p < 4; ++p)
#pragma unroll
            for (int d = 0; d < 3; ++d) {
                int k = 3 * p + d;
                unsigned h = uu[k >> 1];
                h = (k & 1) ? (h & 0xFFFF0000u) : (h << 16);
                y[p][d] = __builtin_bit_cast(float, h);
            }
    } else {
        const f4* C4 = (const f4*)((const float*)coords + 12 * t);
        f4 a = __builtin_nontemporal_load(C4);
        f4 b = __builtin_nontemporal_load(C4 + 1);
        f4 c = __builtin_nontemporal_load(C4 + 2);
        y[0][0] = a.x; y[0][1] = a.y; y[0][2] = a.z;
        y[1][0] = a.w; y[1][1] = b.x; y[1][2] = b.y;
        y[2][0] = b.z; y[2][1] = b.w; y[2][2] = c.x;
        y[3][0] = c.y; y[3][1] = c.z; y[3][2] = c.w;
    }

    auto cell = [](float tt, int* idx, float* f) {
        int v = (int)floorf(tt);
        v = v < 0 ? 0 : (v > TB - 2 ? TB - 2 : v);
        *idx = v; *f = tt - (float)v;
    };

    int ia[4][3];
    float ff[4][3];
#pragma unroll
    for (int p = 0; p < 4; ++p) {
        float t0 = (y[p][0] + 1.0f) * TB_SCALE;
        float t1 = (y[p][1] + 1.0f) * TB_SCALE;
        float t2 = (y[p][2] + 1.0f) * TB_SCALE;
        cell(t0, &ia[p][0], &ff[p][0]);
        cell(t1, &ia[p][1], &ff[p][1]);
        cell(t2, &ia[p][2], &ff[p][2]);
    }

    const s4v* T = (const s4v*)((const char*)ws + TBL_OFF_B);
    s4v ev[4][8];
#pragma unroll
    for (int p = 0; p < 4; ++p) {
        int a0 = tf0(ia[p][0]), a0b = tf0(ia[p][0] + 1);
        int a1 = tf1(ia[p][1]), a1b = tf1(ia[p][1] + 1);
        int a2 = tf2(ia[p][2]), a2b = tf2(ia[p][2] + 1);
        ev[p][0] = T[a0 + a1 + a2];      // c000
        ev[p][1] = T[a0 + a1 + a2b];     // c001
        ev[p][2] = T[a0 + a1b + a2];     // c010
        ev[p][3] = T[a0 + a1b + a2b];    // c011
        ev[p][4] = T[a0b + a1 + a2];     // c100
        ev[p][5] = T[a0b + a1 + a2b];    // c101
        ev[p][6] = T[a0b + a1b + a2];    // c110
        ev[p][7] = T[a0b + a1b + a2b];   // c111
    }

    float c1v[4][3];
#pragma unroll
    for (int p = 0; p < 4; ++p) {
        float f0 = ff[p][0], f1 = ff[p][1], f2 = ff[p][2];
#pragma unroll
        for (int d = 0; d < 3; ++d) {
            float a00 = lerp1((float)ev[p][0][d], (float)ev[p][1][d], f2);
            float a01 = lerp1((float)ev[p][2][d], (float)ev[p][3][d], f2);
            float a10 = lerp1((float)ev[p][4][d], (float)ev[p][5][d], f2);
            float a11 = lerp1((float)ev[p][6][d], (float)ev[p][7][d], f2);
            c1v[p][d] = lerp1(lerp1(a00, a01, f1), lerp1(a10, a11, f1), f0) * QSI;
        }
    }

    {
        float* dst = out + NPTS + 12 * t;
        f4 s0 = {c1v[0][0], c1v[0][1], c1v[0][2], c1v[1][0]};
        f4 s1 = {c1v[1][1], c1v[1][2], c1v[2][0], c1v[2][1]};
        f4 s2 = {c1v[2][2], c1v[3][0], c1v[3][1], c1v[3][2]};
        ((f4*)dst)[0] = s0;
        ((f4*)dst)[1] = s1;
        ((f4*)dst)[2] = s2;
    }

    const unsigned char* VB = (const unsigned char*)ws + VOLB_OFF_B;
    f4 o;
#pragma unroll
    for (int p = 0; p < 4; ++p) {
        float fx = (c1v[p][2] + 1.0f) * 64.0f - 0.5f;
        float fy = (c1v[p][1] + 1.0f) * 64.0f - 0.5f;
        float fz = (c1v[p][0] + 1.0f) * 64.0f - 0.5f;
        float x0f = floorf(fx), y0f = floorf(fy), z0f = floorf(fz);
        float tx = fx - x0f, ty = fy - y0f, tz = fz - z0f;
        int x0 = (int)x0f, y0 = (int)y0f, z0 = (int)z0f;
        int x1 = x0 + 1, y1 = y0 + 1, z1 = z0 + 1;
        auto clampi = [](int v) { return v < 0 ? 0 : (v > 127 ? 127 : v); };
        auto valid = [](int zi, int yi, int xi) -> bool {
            return ((unsigned)zi < 128u) && ((unsigned)yi < 128u) &&
                   ((unsigned)xi < 128u);
        };
        int px0 = bpx(clampi(x0)), px1 = bpx(clampi(x1));
        int py0 = bpy(clampi(y0)), py1 = bpy(clampi(y1));
        int pz0 = bpz(clampi(z0)), pz1 = bpz(clampi(z1));
        float v[8];
        v[0] = (float)VB[pz0 | py0 | px0];
        v[1] = (float)VB[pz0 | py0 | px1];
        v[2] = (float)VB[pz0 | py1 | px0];
        v[3] = (float)VB[pz0 | py1 | px1];
        v[4] = (float)VB[pz1 | py0 | px0];
        v[5] = (float)VB[pz1 | py0 | px1];
        v[6] = (float)VB[pz1 | py1 | px0];
        v[7] = (float)VB[pz1 | py1 | px1];
        if (!valid(z0, y0, x0)) v[0] = 0.f;
        if (!valid(z0, y0, x1)) v[1] = 0.f;
        if (!valid(z0, y1, x0)) v[2] = 0.f;
        if (!valid(z0, y1, x1)) v[3] = 0.f;
        if (!valid(z1, y0, x0)) v[4] = 0.f;
        if (!valid(z1, y0, x1)) v[5] = 0.f;
        if (!valid(z1, y1, x0)) v[6] = 0.f;
        if (!valid(z1, y1, x1)) v[7] = 0.f;
        float sraw =
            v[0] * (1.f - tz) * (1.f - ty) * (1.f - tx) +
            v[1] * (1.f - tz) * (1.f - ty) * tx +
            v[2] * (1.f - tz) * ty * (1.f - tx) +
            v[3] * (1.f - tz) * ty * tx +
            v[4] * tz * (1.f - ty) * (1.f - tx) +
            v[5] * tz * (1.f - ty) * tx +
            v[6] * tz * ty * (1.f - tx) +
            v[7] * tz * ty * tx;
        o[p] = __builtin_fmaf(sraw, 2.0f / 255.0f, -1.0f);
    }
    ((f4*)(out + 4 * t))[0] = o;
}

// Fallback direct kernel (2 pts/thread) for small ws_size.
__global__ __launch_bounds__(64) void diffeo_kernel(
    const void* __restrict__ coords,
    const float* __restrict__ ws,
    const void* __restrict__ vol,
    float* __restrict__ out) {
    int t = blockIdx.x * 64 + threadIdx.x;   // pair index
    if (t >= NPTS / 2) return;

    const int* flags = (const int*)(ws + 1024);
    int cbf = flags[0];
    int vbf = flags[1];

    v2f y0, y1, y2;
    if (cbf) {
        const __hip_bfloat16* C = (const __hip_bfloat16*)coords;
        int b = 6 * t;
        y0.x = bf2f(C[b + 0]); y1.x = bf2f(C[b + 1]); y2.x = bf2f(C[b + 2]);
        y0.y = bf2f(C[b + 3]); y1.y = bf2f(C[b + 4]); y2.y = bf2f(C[b + 5]);
    } else {
        const float* C = (const float*)coords;
        int b = 6 * t;
        y0.x = C[b + 0]; y1.x = C[b + 1]; y2.x = C[b + 2];
        y0.y = C[b + 3]; y1.y = C[b + 4]; y2.y = C[b + 5];
    }

    integrate2(ws, y0, y1, y2);

    int b = 6 * t;
    out[NPTS + b + 0] = y0.x; out[NPTS + b + 1] = y1.x; out[NPTS + b + 2] = y2.x;
    out[NPTS + b + 3] = y0.y; out[NPTS + b + 4] = y1.y; out[NPTS + b + 5] = y2.y;

    float sA = sample3d(vol, vbf, y0.x, y1.x, y2.x);
    float sB = sample3d(vol, vbf, y0.y, y1.y, y2.y);
    out[2 * t + 0] = __builtin_fmaf(2.0f, sA, -1.0f);
    out[2 * t + 1] = __builtin_fmaf(2.0f, sB, -1.0f);
}

extern "C" void kernel_launch(void* const* d_in, const int* in_sizes, int n_in,
                              void* d_out, int out_size, void* d_ws, size_t ws_size,
                              hipStream_t stream) {
    const void* coords = d_in[0];
    const void* W1_0 = d_in[1];
    const void* b1_0 = d_in[2];
    const void* W2_0 = d_in[3];
    const void* b2_0 = d_in[4];
    const void* W1_1 = d_in[5];
    const void* b1_1 = d_in[6];
    const void* W2_1 = d_in[7];
    const void* b2_1 = d_in[8];
    const void* vol  = d_in[9];
    float* out = (float*)d_out;
    float* ws = (float*)d_ws;

    if (ws_size >= WS_NEED) {
        prep_kernel<<<BUILD_BLOCKS + CONV_BLOCKS, 256, 0, stream>>>(
            W1_0, b1_0, W2_0, b2_0, W1_1, b1_1, W2_1, b2_1, vol, ws);
        query_kernel<<<NPTS / 1024, 256, 0, stream>>>(coords, ws, out);
    } else {
        setup_kernel<<<1, 1024, 0, stream>>>(coords, W1_0, b1_0, W2_0, b2_0,
                                             W1_1, b1_1, W2_1, b2_1, vol, ws);
        diffeo_kernel<<<(NPTS / 2) / 64, 64, 0, stream>>>(coords, ws, vol, out);
    }
}

// Round 9
// 144.555 us; speedup vs baseline: 1.2063x; 1.0387x over previous
//
#include <hip/hip_runtime.h>
#include <hip/hip_bf16.h>

#define NPTS (96 * 96 * 96)   // 884736 points
#define HID 64
#define H_EFF 0.2f            // RK4 1 step/ODE — verified error << bf16 floor

// CONCURRENCY MODEL (R8 synthesis): query is L2-latency/MSHR bound.
// time ~ total L2 round trips / outstanding-miss capacity; capacity scales
// with resident waves. R0 (8 lines/pt, 55% occ) == R8 (4.6 lines/pt, 22%
// occ) == 46us. Footprint reductions (R4 undup, R8 brick) are real but were
// cancelled by grid shrink (4pt/thread -> 864 blocks = 42% occ cap).
// THIS ROUND: 2 pts/thread -> 1728 blocks (~84% occ cap), layouts unchanged.
// R7 LESSON kept: stride-4 j-split, conflict-free LDS weight reads.
// R3 LESSON kept: gather set 1.04+2.1 MB < 4 MiB/XCD L2.
#define TB  49
#define TB2 (TB * TB)         // 2401
#define TB3 (TB * TB * TB)    // 117649
#define TB_SCALE 24.0f
#define TB_INV   0.0416666679f
#define QS   8192.0f
#define QSI  (1.0f / 8192.0f)
#define TBL_OFF_B 4128
#define TBL_BRICK_BYTES 1040000   // 25*25*13 bricks * 128B
#define VOLB_OFF_B 1044480        // 128B-aligned after table
#define VOL_N   (128 * 128 * 128)
#define WS_NEED ((size_t)VOLB_OFF_B + (size_t)VOL_N)

#define BUILD_BLOCKS 920      // 4 lanes per point-pair: 235300 thr / 256
#define CONV_BLOCKS  1024     // VOL_N / (256*8)

typedef float v2f __attribute__((ext_vector_type(2)));
typedef float f4  __attribute__((ext_vector_type(4)));
typedef unsigned u2 __attribute__((ext_vector_type(2)));
typedef unsigned u4 __attribute__((ext_vector_type(4)));
typedef short s4v __attribute__((ext_vector_type(4)));

__device__ __forceinline__ float bf2f(const __hip_bfloat16 v) {
    return __bfloat162float(v);
}
__device__ __forceinline__ v2f splat(float x) { v2f r; r.x = x; r.y = x; return r; }
__device__ __forceinline__ v2f vfma(v2f a, v2f b, v2f c) {
    return __builtin_elementwise_fma(a, b, c);
}
__device__ __forceinline__ float lerp1(float a, float b, float f) {
    return __builtin_fmaf(f, b - a, a);
}

// Vol brick address pieces: [bz:5][by:5][bx:4][z&3:2][y&3:2][x&7:3].
__device__ __forceinline__ int bpx(int x) { return ((x >> 3) << 7) | (x & 7); }
__device__ __forceinline__ int bpy(int y) { return ((y >> 2) << 11) | ((y & 3) << 3); }
__device__ __forceinline__ int bpz(int z) { return ((z >> 2) << 16) | ((z & 3) << 5); }

// Table brick addressing (8B entries; brick = 2 i0 x 2 i1 x 4 i2 = 16 entries
// = 128B; brick grid 25 x 25 x 13 row-major). Additive decomposition.
__device__ __forceinline__ int tf0(int i0) { return (i0 >> 1) * 5200 + (i0 & 1) * 8; }
__device__ __forceinline__ int tf1(int i1) { return (i1 >> 1) * 208 + (i1 & 1) * 4; }
__device__ __forceinline__ int tf2(int i2) { return (i2 >> 2) * 16 + (i2 & 3); }

__device__ __forceinline__ int detect_bf16(const void* p, int tid, int* sflag) {
    if (tid < 64) {
        unsigned e = (((const unsigned short*)p)[tid] >> 7) & 0xFFu;
        unsigned long long m = __ballot(e >= 97u && e <= 129u);
        if (tid == 0) *sflag = (__popcll(m) >= 52) ? 1 : 0;
    }
    __syncthreads();
    return *sflag;
}

// ---------------------------------------------------------------------------
// setup_kernel: FALLBACK-PATH ONLY (diffeo needs folded weights + flags in ws).
// ---------------------------------------------------------------------------
__global__ void setup_kernel(
    const void* __restrict__ coords,
    const void* __restrict__ W1_0, const void* __restrict__ b1_0,
    const void* __restrict__ W2_0, const void* __restrict__ b2_0,
    const void* __restrict__ W1_1, const void* __restrict__ b1_1,
    const void* __restrict__ W2_1, const void* __restrict__ b2_1,
    const void* __restrict__ vol,
    float* __restrict__ ws) {
    __shared__ int sflags[3];
    int tid = threadIdx.x;
    if (tid < 64) {
        auto sane = [](const void* p, int i) -> bool {
            unsigned e = (((const unsigned short*)p)[i] >> 7) & 0xFFu;
            return e >= 97u && e <= 129u;
        };
        unsigned long long m;
        m = __ballot(sane(W1_0, tid));
        if (tid == 0) sflags[2] = (__popcll(m) >= 52) ? 1 : 0;
        m = __ballot(sane(coords, tid));
        if (tid == 0) sflags[0] = (__popcll(m) >= 52) ? 1 : 0;
        m = __ballot(sane(vol, tid));
        if (tid == 0) sflags[1] = (__popcll(m) >= 52) ? 1 : 0;
    }
    __syncthreads();
    int isbf = sflags[2];
    const float K = 2.88539008177792681472f;  // 2/ln(2)
    int ode = tid >> 9;
    int r = tid & 511;
    const void* W1 = ode ? W1_1 : W1_0;
    const void* b1 = ode ? b1_1 : b1_0;
    const void* W2 = ode ? W2_1 : W2_0;
    const void* b2 = ode ? b2_1 : b2_0;
    auto ld = [&](const void* p, int idx) -> float {
        return isbf ? bf2f(((const __hip_bfloat16*)p)[idx]) : ((const float*)p)[idx];
    };
    float v = 0.0f;
    if (r < 192)       v = K * ld(W1, r);
    else if (r < 256)  v = K * ld(b1, r - 192);
    else if (r < 448)  v = -2.0f * ld(W2, r - 256);
    else if (r < 451) {
        int k = r - 448;
        float s = ld(b2, k);
        for (int j = 0; j < HID; ++j) s += ld(W2, 3 * j + k);
        v = s;
    }
    ws[(ode << 9) + r] = v;
    if (tid < 2) ((int*)(ws + 1024))[tid] = sflags[tid];
}

// Pair-point MLP (fallback path, lane-uniform weights from global ws).
__device__ __forceinline__ void mlp_f2(const float* __restrict__ w,
                                       v2f y0, v2f y1, v2f y2,
                                       v2f& o0, v2f& o1, v2f& o2) {
    v2f a0 = splat(w[448]), a1 = splat(w[449]), a2 = splat(w[450]);
#pragma unroll 8
    for (int j = 0; j < HID; ++j) {
        v2f pre = vfma(y0, splat(w[j]),
                  vfma(y1, splat(w[64 + j]),
                  vfma(y2, splat(w[128 + j]), splat(w[192 + j]))));
        v2f e;
        e.x = __builtin_amdgcn_exp2f(pre.x);
        e.y = __builtin_amdgcn_exp2f(pre.y);
        v2f q = e + splat(1.0f);
        float rP = __builtin_amdgcn_rcpf(q.x * q.y);
        v2f r;
        r.x = q.y * rP;
        r.y = q.x * rP;
        a0 = vfma(r, splat(w[256 + 3 * j + 0]), a0);
        a1 = vfma(r, splat(w[256 + 3 * j + 1]), a1);
        a2 = vfma(r, splat(w[256 + 3 * j + 2]), a2);
    }
    o0 = a0; o1 = a1; o2 = a2;
}

__device__ __forceinline__ void integrate2(const float* __restrict__ ws,
                                           v2f& y0, v2f& y1, v2f& y2) {
    const float h = H_EFF;
#pragma unroll 1
    for (int ode = 0; ode < 2; ++ode) {
        const float* __restrict__ w = ws + (ode << 9);
        v2f k0 = splat(0.f), k1 = splat(0.f), k2 = splat(0.f);
        v2f s0 = splat(0.f), s1 = splat(0.f), s2 = splat(0.f);
#pragma unroll 1
        for (int e = 0; e < 4; ++e) {
            float ae = (e == 0) ? 0.0f : ((e == 3) ? h : 0.5f * h);
            float we = (e == 1 || e == 2) ? 2.0f : 1.0f;
            v2f aev = splat(ae), wev = splat(we);
            v2f f0, f1, f2;
            mlp_f2(w, vfma(aev, k0, y0), vfma(aev, k1, y1), vfma(aev, k2, y2),
                   f0, f1, f2);
            k0 = f0; k1 = f1; k2 = f2;
            s0 = vfma(wev, k0, s0);
            s1 = vfma(wev, k1, s1);
            s2 = vfma(wev, k2, s2);
        }
        v2f h6 = splat(h / 6.0f);
        y0 = vfma(h6, s0, y0);
        y1 = vfma(h6, s1, y1);
        y2 = vfma(h6, s2, y2);
    }
}

// ---------------------------------------------------------------------------
// prep_kernel: fused build (blocks < BUILD_BLOCKS) + vol conversion (rest).
// Build: lane-QUAD per point-pair (v2f); lane h sums j in {h, h+4, ..., h+60}
// (stride-4 -> conflict-free LDS reads, R7 lesson); 2-step shfl_xor combine.
// ---------------------------------------------------------------------------
__global__ __launch_bounds__(256) void prep_kernel(
    const void* __restrict__ W1_0, const void* __restrict__ b1_0,
    const void* __restrict__ W2_0, const void* __restrict__ b2_0,
    const void* __restrict__ W1_1, const void* __restrict__ b1_1,
    const void* __restrict__ W2_1, const void* __restrict__ b2_1,
    const void* __restrict__ vol,
    float* __restrict__ ws) {
    int tid = threadIdx.x;
    if (blockIdx.x < BUILD_BLOCKS) {
        __shared__ int sflag;
        __shared__ f4 sw1[2][64];     // {K*W1[0][j], K*W1[1][j], K*W1[2][j], K*b1[j]}
        __shared__ f4 sw2[2][64];     // {-2*W2[j][0], -2*W2[j][1], -2*W2[j][2], 0}
        __shared__ float sb2[2][4];   // b2'' per ode
        int isbf = detect_bf16(W1_0, tid, &sflag);
        const float K = 2.88539008177792681472f;
        auto ld = [&](const void* p, int idx) -> float {
            return isbf ? bf2f(((const __hip_bfloat16*)p)[idx]) : ((const float*)p)[idx];
        };
        {
            int ode = (tid >> 6) & 1;
            int j = tid & 63;
            const void* W1 = ode ? W1_1 : W1_0;
            const void* b1 = ode ? b1_1 : b1_0;
            const void* W2 = ode ? W2_1 : W2_0;
            if (tid < 128) {
                f4 c = { K * ld(W1, j), K * ld(W1, 64 + j),
                         K * ld(W1, 128 + j), K * ld(b1, j) };
                sw1[ode][j] = c;
            } else {
                f4 c = { -2.f * ld(W2, 3 * j + 0), -2.f * ld(W2, 3 * j + 1),
                         -2.f * ld(W2, 3 * j + 2), 0.f };
                sw2[ode][j] = c;
            }
            if (tid < 6) {
                int o = tid / 3, k = tid - 3 * o;
                const void* W2o = o ? W2_1 : W2_0;
                const void* b2o = o ? b2_1 : b2_0;
                float s = ld(b2o, k);
                for (int jj = 0; jj < HID; ++jj) s += ld(W2o, 3 * jj + k);
                sb2[o][k] = s;
            }
        }
        __syncthreads();

        int gtid = blockIdx.x * 256 + tid;
        int lp = gtid >> 2;       // point-pair index
        int h  = gtid & 3;        // j-residue class (stride-4)
        int nA = 2 * lp;
        if (nA >= TB3) return;
        int nB = nA + 1;
        int nBc = nB < TB3 ? nB : (TB3 - 1);

        auto node_idx = [](int n, int* i0, int* i1, int* i2) {
            *i0 = n / TB2;
            int rem = n - *i0 * TB2;
            *i1 = rem / TB;
            *i2 = rem - *i1 * TB;
        };
        int iA0, iA1, iA2, iB0, iB1, iB2;
        node_idx(nA,  &iA0, &iA1, &iA2);
        node_idx(nBc, &iB0, &iB1, &iB2);
        v2f y0, y1, y2;
        y0.x = __builtin_fmaf((float)iA0, TB_INV, -1.0f);
        y1.x = __builtin_fmaf((float)iA1, TB_INV, -1.0f);
        y2.x = __builtin_fmaf((float)iA2, TB_INV, -1.0f);
        y0.y = __builtin_fmaf((float)iB0, TB_INV, -1.0f);
        y1.y = __builtin_fmaf((float)iB1, TB_INV, -1.0f);
        y2.y = __builtin_fmaf((float)iB2, TB_INV, -1.0f);

        const float hh = H_EFF;
#pragma unroll 1
        for (int ode = 0; ode < 2; ++ode) {
            const f4* __restrict__ w1 = sw1[ode];
            const f4* __restrict__ w2 = sw2[ode];
            v2f b2v0 = h ? splat(0.f) : splat(sb2[ode][0]);
            v2f b2v1 = h ? splat(0.f) : splat(sb2[ode][1]);
            v2f b2v2 = h ? splat(0.f) : splat(sb2[ode][2]);
            v2f k0 = splat(0.f), k1 = splat(0.f), k2 = splat(0.f);
            v2f s0 = splat(0.f), s1 = splat(0.f), s2 = splat(0.f);
#pragma unroll 1
            for (int e = 0; e < 4; ++e) {
                float ae = (e == 0) ? 0.0f : ((e == 3) ? hh : 0.5f * hh);
                float we = (e == 1 || e == 2) ? 2.0f : 1.0f;
                v2f aev = splat(ae), wev = splat(we);
                v2f z0 = vfma(aev, k0, y0);
                v2f z1 = vfma(aev, k1, y1);
                v2f z2 = vfma(aev, k2, y2);
                v2f a0 = b2v0, a1 = b2v1, a2 = b2v2;
#pragma unroll 8
                for (int jj = 0; jj < 16; ++jj) {
                    // stride-4: quad lanes read 16B-consecutive slots.
                    f4 c1 = w1[4 * jj + h];
                    v2f pre = vfma(z0, splat(c1.x),
                              vfma(z1, splat(c1.y),
                              vfma(z2, splat(c1.z), splat(c1.w))));
                    v2f ev;
                    ev.x = __builtin_amdgcn_exp2f(pre.x);
                    ev.y = __builtin_amdgcn_exp2f(pre.y);
                    v2f q = ev + splat(1.0f);
                    float rP = __builtin_amdgcn_rcpf(q.x * q.y);
                    v2f r;
                    r.x = q.y * rP;
                    r.y = q.x * rP;
                    f4 c2 = w2[4 * jj + h];
                    a0 = vfma(r, splat(c2.x), a0);
                    a1 = vfma(r, splat(c2.y), a1);
                    a2 = vfma(r, splat(c2.z), a2);
                }
                // combine 4 lane-quarters (commutative swaps -> bit-identical)
                v2f t;
                t.x = __shfl_xor(a0.x, 1); t.y = __shfl_xor(a0.y, 1); a0 += t;
                t.x = __shfl_xor(a1.x, 1); t.y = __shfl_xor(a1.y, 1); a1 += t;
                t.x = __shfl_xor(a2.x, 1); t.y = __shfl_xor(a2.y, 1); a2 += t;
                t.x = __shfl_xor(a0.x, 2); t.y = __shfl_xor(a0.y, 2); a0 += t;
                t.x = __shfl_xor(a1.x, 2); t.y = __shfl_xor(a1.y, 2); a1 += t;
                t.x = __shfl_xor(a2.x, 2); t.y = __shfl_xor(a2.y, 2); a2 += t;
                k0 = a0; k1 = a1; k2 = a2;
                s0 = vfma(wev, k0, s0);
                s1 = vfma(wev, k1, s1);
                s2 = vfma(wev, k2, s2);
            }
            v2f h6 = splat(hh / 6.0f);
            y0 = vfma(h6, s0, y0);
            y1 = vfma(h6, s1, y1);
            y2 = vfma(h6, s2, y2);
        }

        if (h == 0) {
            auto quant = [](float v) -> short {
                float q = v * QS;
                q = q < -32767.f ? -32767.f : (q > 32767.f ? 32767.f : q);
                return (short)(int)rintf(q);
            };
            s4v* T = (s4v*)((char*)ws + TBL_OFF_B);
            s4v qA = { quant(y0.x), quant(y1.x), quant(y2.x), 0 };
            T[tf0(iA0) + tf1(iA1) + tf2(iA2)] = qA;
            if (nB < TB3) {
                s4v qB = { quant(y0.y), quant(y1.y), quant(y2.y), 0 };
                T[tf0(iB0) + tf1(iB1) + tf2(iB2)] = qB;
            }
        }
    } else {
        // ------- conv: quantize vol to u8 in 128B-brick layout, 8 vox/thread
        __shared__ int svf;
        int vbf = detect_bf16(vol, tid, &svf);
        int g = (blockIdx.x - BUILD_BLOCKS) * 256 + tid;
        int d0 = g * 8;                        // 8 consecutive bricked bytes
        int x0 = ((d0 >> 7) & 15) << 3;        // d0&7 == 0
        int yy = (((d0 >> 11) & 31) << 2) | ((d0 >> 3) & 3);
        int zz = (((d0 >> 16) & 31) << 2) | ((d0 >> 5) & 3);
        int src = (zz << 14) | (yy << 7) | x0; // 8 consecutive source voxels
        float v[8];
        if (vbf) {
            u4 w = *(const u4*)((const unsigned short*)vol + src);
#pragma unroll
            for (int i = 0; i < 4; ++i) {
                unsigned ww = w[i];
                v[2 * i + 0] = __builtin_bit_cast(float, ww << 16);
                v[2 * i + 1] = __builtin_bit_cast(float, ww & 0xFFFF0000u);
            }
        } else {
            const f4* F = (const f4*)((const float*)vol + src);
            f4 A = F[0], B = F[1];
            v[0] = A.x; v[1] = A.y; v[2] = A.z; v[3] = A.w;
            v[4] = B.x; v[5] = B.y; v[6] = B.z; v[7] = B.w;
        }
        unsigned q[8];
#pragma unroll
        for (int i = 0; i < 8; ++i) {
            float qq = __builtin_fmaf(v[i], 255.0f, 0.5f);
            qq = qq < 0.f ? 0.f : (qq > 255.f ? 255.f : qq);
            q[i] = (unsigned)qq;
        }
        u2 pk;
        pk.x = q[0] | (q[1] << 8) | (q[2] << 16) | (q[3] << 24);
        pk.y = q[4] | (q[5] << 8) | (q[6] << 16) | (q[7] << 24);
        *(u2*)((unsigned char*)ws + VOLB_OFF_B + d0) = pk;
    }
}

// fp-source grid-sample for the fallback path.
__device__ __forceinline__ float sample3d(const void* __restrict__ vol, int vbf,
                                          float cz, float cy, float cx) {
    float fx = (cx + 1.0f) * 64.0f - 0.5f;
    float fy = (cy + 1.0f) * 64.0f - 0.5f;
    float fz = (cz + 1.0f) * 64.0f - 0.5f;
    float x0f = floorf(fx), y0f = floorf(fy), z0f = floorf(fz);
    float tx = fx - x0f, ty = fy - y0f, tz = fz - z0f;
    int x0 = (int)x0f, y0 = (int)y0f, z0 = (int)z0f;
    int x1 = x0 + 1, y1 = y0 + 1, z1 = z0 + 1;
    auto clampi = [](int v) { return v < 0 ? 0 : (v > 127 ? 127 : v); };
    auto valid = [](int zi, int yi, int xi) -> bool {
        return ((unsigned)zi < 128u) && ((unsigned)yi < 128u) && ((unsigned)xi < 128u);
    };
    int xc0 = clampi(x0), xc1 = clampi(x1);
    int yc0 = clampi(y0), yc1 = clampi(y1);
    int zc0 = clampi(z0), zc1 = clampi(z1);
    int idx[8] = {
        (zc0 << 14) | (yc0 << 7) | xc0, (zc0 << 14) | (yc0 << 7) | xc1,
        (zc0 << 14) | (yc1 << 7) | xc0, (zc0 << 14) | (yc1 << 7) | xc1,
        (zc1 << 14) | (yc0 << 7) | xc0, (zc1 << 14) | (yc0 << 7) | xc1,
        (zc1 << 14) | (yc1 << 7) | xc0, (zc1 << 14) | (yc1 << 7) | xc1 };
    float v[8];
    if (vbf) {
        const __hip_bfloat16* V = (const __hip_bfloat16*)vol;
#pragma unroll
        for (int q = 0; q < 8; ++q) v[q] = bf2f(V[idx[q]]);
    } else {
        const float* V = (const float*)vol;
#pragma unroll
        for (int q = 0; q < 8; ++q) v[q] = V[idx[q]];
    }
    if (!valid(z0, y0, x0)) v[0] = 0.f;
    if (!valid(z0, y0, x1)) v[1] = 0.f;
    if (!valid(z0, y1, x0)) v[2] = 0.f;
    if (!valid(z0, y1, x1)) v[3] = 0.f;
    if (!valid(z1, y0, x0)) v[4] = 0.f;
    if (!valid(z1, y0, x1)) v[5] = 0.f;
    if (!valid(z1, y1, x0)) v[6] = 0.f;
    if (!valid(z1, y1, x1)) v[7] = 0.f;
    return v[0] * (1.f - tz) * (1.f - ty) * (1.f - tx) +
           v[1] * (1.f - tz) * (1.f - ty) * tx +
           v[2] * (1.f - tz) * ty * (1.f - tx) +
           v[3] * (1.f - tz) * ty * tx +
           v[4] * tz * (1.f - ty) * (1.f - tx) +
           v[5] * tz * (1.f - ty) * tx +
           v[6] * tz * ty * (1.f - tx) +
           v[7] * tz * ty * tx;
}

// ---------------------------------------------------------------------------
// Query: 2 pts/thread, 1728 blocks (~84% occ cap). Bricked table + vol.
// ---------------------------------------------------------------------------
__global__ __launch_bounds__(256) void query_kernel(
    const void* __restrict__ coords,
    const float* __restrict__ ws,
    float* __restrict__ out) {
    __shared__ int scf;
    int cbf = detect_bf16(coords, threadIdx.x, &scf);
    int t = blockIdx.x * 256 + threadIdx.x;   // pair-of-points index
    if (t >= NPTS / 2) return;

    float y[2][3];
    if (cbf) {
        // 6 bf16 = 12 B at offset 12t: 4B-aligned -> 3x dword
        const unsigned* C1 = (const unsigned*)((const unsigned short*)coords + 6 * t);
        unsigned uu[3];
        uu[0] = C1[0]; uu[1] = C1[1]; uu[2] = C1[2];
#pragma unroll
        for (int p = 0; p < 2; ++p)
#pragma unroll
            for (int d = 0; d < 3; ++d) {
                int k = 3 * p + d;
                unsigned h = uu[k >> 1];
                h = (k & 1) ? (h & 0xFFFF0000u) : (h << 16);
                y[p][d] = __builtin_bit_cast(float, h);
            }
    } else {
        // 6 floats = 24 B at offset 24t: 8B-aligned -> dwordx4 + dwordx2
        const float* C = (const float*)coords + 6 * t;
        f4 a = *(const f4*)C;
        v2f b = *(const v2f*)(C + 4);
        y[0][0] = a.x; y[0][1] = a.y; y[0][2] = a.z;
        y[1][0] = a.w; y[1][1] = b.x; y[1][2] = b.y;
    }

    auto cell = [](float tt, int* idx, float* f) {
        int v = (int)floorf(tt);
        v = v < 0 ? 0 : (v > TB - 2 ? TB - 2 : v);
        *idx = v; *f = tt - (float)v;
    };

    int ia[2][3];
    float ff[2][3];
#pragma unroll
    for (int p = 0; p < 2; ++p) {
        float t0 = (y[p][0] + 1.0f) * TB_SCALE;
        float t1 = (y[p][1] + 1.0f) * TB_SCALE;
        float t2 = (y[p][2] + 1.0f) * TB_SCALE;
        cell(t0, &ia[p][0], &ff[p][0]);
        cell(t1, &ia[p][1], &ff[p][1]);
        cell(t2, &ia[p][2], &ff[p][2]);
    }

    const s4v* T = (const s4v*)((const char*)ws + TBL_OFF_B);
    s4v ev[2][8];
#pragma unroll
    for (int p = 0; p < 2; ++p) {
        int a0 = tf0(ia[p][0]), a0b = tf0(ia[p][0] + 1);
        int a1 = tf1(ia[p][1]), a1b = tf1(ia[p][1] + 1);
        int a2 = tf2(ia[p][2]), a2b = tf2(ia[p][2] + 1);
        ev[p][0] = T[a0 + a1 + a2];      // c000
        ev[p][1] = T[a0 + a1 + a2b];     // c001
        ev[p][2] = T[a0 + a1b + a2];     // c010
        ev[p][3] = T[a0 + a1b + a2b];    // c011
        ev[p][4] = T[a0b + a1 + a2];     // c100
        ev[p][5] = T[a0b + a1 + a2b];    // c101
        ev[p][6] = T[a0b + a1b + a2];    // c110
        ev[p][7] = T[a0b + a1b + a2b];   // c111
    }

    float c1v[2][3];
#pragma unroll
    for (int p = 0; p < 2; ++p) {
        float f0 = ff[p][0], f1 = ff[p][1], f2 = ff[p][2];
#pragma unroll
        for (int d = 0; d < 3; ++d) {
            float a00 = lerp1((float)ev[p][0][d], (float)ev[p][1][d], f2);
            float a01 = lerp1((float)ev[p][2][d], (float)ev[p][3][d], f2);
            float a10 = lerp1((float)ev[p][4][d], (float)ev[p][5][d], f2);
            float a11 = lerp1((float)ev[p][6][d], (float)ev[p][7][d], f2);
            c1v[p][d] = lerp1(lerp1(a00, a01, f1), lerp1(a10, a11, f1), f0) * QSI;
        }
    }

    {
        // c1 out: 6 floats at offset 24t: dwordx4 + dwordx2 (8B aligned).
        float* dst = out + NPTS + 6 * t;
        f4 s0 = {c1v[0][0], c1v[0][1], c1v[0][2], c1v[1][0]};
        v2f s1 = {c1v[1][1], c1v[1][2]};
        *(f4*)dst = s0;
        *(v2f*)(dst + 4) = s1;
    }

    const unsigned char* VB = (const unsigned char*)ws + VOLB_OFF_B;
    v2f o;
#pragma unroll
    for (int p = 0; p < 2; ++p) {
        float fx = (c1v[p][2] + 1.0f) * 64.0f - 0.5f;
        float fy = (c1v[p][1] + 1.0f) * 64.0f - 0.5f;
        float fz = (c1v[p][0] + 1.0f) * 64.0f - 0.5f;
        float x0f = floorf(fx), y0f = floorf(fy), z0f = floorf(fz);
        float tx = fx - x0f, ty = fy - y0f, tz = fz - z0f;
        int x0 = (int)x0f, y0 = (int)y0f, z0 = (int)z0f;
        int x1 = x0 + 1, y1 = y0 + 1, z1 = z0 + 1;
        auto clampi = [](int v) { return v < 0 ? 0 : (v > 127 ? 127 : v); };
        auto valid = [](int zi, int yi, int xi) -> bool {
            return ((unsigned)zi < 128u) && ((unsigned)yi < 128u) &&
                   ((unsigned)xi < 128u);
        };
        int px0 = bpx(clampi(x0)), px1 = bpx(clampi(x1));
        int py0 = bpy(clampi(y0)), py1 = bpy(clampi(y1));
        int pz0 = bpz(clampi(z0)), pz1 = bpz(clampi(z1));
        float v[8];
        v[0] = (float)VB[pz0 | py0 | px0];
        v[1] = (float)VB[pz0 | py0 | px1];
        v[2] = (float)VB[pz0 | py1 | px0];
        v[3] = (float)VB[pz0 | py1 | px1];
        v[4] = (float)VB[pz1 | py0 | px0];
        v[5] = (float)VB[pz1 | py0 | px1];
        v[6] = (float)VB[pz1 | py1 | px0];
        v[7] = (float)VB[pz1 | py1 | px1];
        if (!valid(z0, y0, x0)) v[0] = 0.f;
        if (!valid(z0, y0, x1)) v[1] = 0.f;
        if (!valid(z0, y1, x0)) v[2] = 0.f;
        if (!valid(z0, y1, x1)) v[3] = 0.f;
        if (!valid(z1, y0, x0)) v[4] = 0.f;
        if (!valid(z1, y0, x1)) v[5] = 0.f;
        if (!valid(z1, y1, x0)) v[6] = 0.f;
        if (!valid(z1, y1, x1)) v[7] = 0.f;
        float sraw =
            v[0] * (1.f - tz) * (1.f - ty) * (1.f - tx) +
            v[1] * (1.f - tz) * (1.f - ty) * tx +
            v[2] * (1.f - tz) * ty * (1.f - tx) +
            v[3] * (1.f - tz) * ty * tx +
            v[4] * tz * (1.f - ty) * (1.f - tx) +
            v[5] * tz * (1.f - ty) * tx +
            v[6] * tz * ty * (1.f - tx) +
            v[7] * tz * ty * tx;
        o[p] = __builtin_fmaf(sraw, 2.0f / 255.0f, -1.0f);
    }
    *(v2f*)(out + 2 * t) = o;
}

// Fallback direct kernel (2 pts/thread) for small ws_size.
__global__ __launch_bounds__(64) void diffeo_kernel(
    const void* __restrict__ coords,
    const float* __restrict__ ws,
    const void* __restrict__ vol,
    float* __restrict__ out) {
    int t = blockIdx.x * 64 + threadIdx.x;   // pair index
    if (t >= NPTS / 2) return;

    const int* flags = (const int*)(ws + 1024);
    int cbf = flags[0];
    int vbf = flags[1];

    v2f y0, y1, y2;
    if (cbf) {
        const __hip_bfloat16* C = (const __hip_bfloat16*)coords;
        int b = 6 * t;
        y0.x = bf2f(C[b + 0]); y1.x = bf2f(C[b + 1]); y2.x = bf2f(C[b + 2]);
        y0.y = bf2f(C[b + 3]); y1.y = bf2f(C[b + 4]); y2.y = bf2f(C[b + 5]);
    } else {
        const float* C = (const float*)coords;
        int b = 6 * t;
        y0.x = C[b + 0]; y1.x = C[b + 1]; y2.x = C[b + 2];
        y0.y = C[b + 3]; y1.y = C[b + 4]; y2.y = C[b + 5];
    }

    integrate2(ws, y0, y1, y2);

    int b = 6 * t;
    out[NPTS + b + 0] = y0.x; out[NPTS + b + 1] = y1.x; out[NPTS + b + 2] = y2.x;
    out[NPTS + b + 3] = y0.y; out[NPTS + b + 4] = y1.y; out[NPTS + b + 5] = y2.y;

    float sA = sample3d(vol, vbf, y0.x, y1.x, y2.x);
    float sB = sample3d(vol, vbf, y0.y, y1.y, y2.y);
    out[2 * t + 0] = __builtin_fmaf(2.0f, sA, -1.0f);
    out[2 * t + 1] = __builtin_fmaf(2.0f, sB, -1.0f);
}

extern "C" void kernel_launch(void* const* d_in, const int* in_sizes, int n_in,
                              void* d_out, int out_size, void* d_ws, size_t ws_size,
                              hipStream_t stream) {
    const void* coords = d_in[0];
    const void* W1_0 = d_in[1];
    const void* b1_0 = d_in[2];
    const void* W2_0 = d_in[3];
    const void* b2_0 = d_in[4];
    const void* W1_1 = d_in[5];
    const void* b1_1 = d_in[6];
    const void* W2_1 = d_in[7];
    const void* b2_1 = d_in[8];
    const void* vol  = d_in[9];
    float* out = (float*)d_out;
    float* ws = (float*)d_ws;

    if (ws_size >= WS_NEED) {
        prep_kernel<<<BUILD_BLOCKS + CONV_BLOCKS, 256, 0, stream>>>(
            W1_0, b1_0, W2_0, b2_0, W1_1, b1_1, W2_1, b2_1, vol, ws);
        query_kernel<<<(NPTS / 2) / 256, 256, 0, stream>>>(coords, ws, out);
    } else {
        setup_kernel<<<1, 1024, 0, stream>>>(coords, W1_0, b1_0, W2_0, b2_0,
                                             W1_1, b1_1, W2_1, b2_1, vol, ws);
        diffeo_kernel<<<(NPTS / 2) / 64, 64, 0, stream>>>(coords, ws, vol, out);
    }
}

// Round 10
// 135.348 us; speedup vs baseline: 1.2884x; 1.0680x over previous
//
#include <hip/hip_runtime.h>
#include <hip/hip_bf16.h>

#define NPTS (96 * 96 * 96)   // 884736 points
#define HID 64
#define H_EFF 0.2f            // RK4 1 step/ODE — verified error << bf16 floor

// CONCURRENCY MODEL (R8/R9 confirmed): query is L2-latency/MSHR bound;
// time ~ (lines/pt x NPTS) / (resident waves x in-flight per wave).
// R8: 4pt/thread @22% occ = 46us. R9: 2pt @ ~45% = ~35us. This round:
// 1pt/thread -> 3456 blocks, 100% occ cap. Line floor ~28us
// (4.8 lines/pt / 8 req/cy/XCD / 8 XCD / 2.4GHz).
// Layouts (bit-identical values): bricked int16 table 2x2x4/128B
// (E[2.81] lines), bricked u8 vol 4x4x8/128B (E[1.76]); set 3.14MB <
// 4MiB/XCD L2 (R3 rule). R7 lesson: stride-4 j-split in build keeps LDS
// weight reads conflict-free.
#define TB  49
#define TB2 (TB * TB)         // 2401
#define TB3 (TB * TB * TB)    // 117649
#define TB_SCALE 24.0f
#define TB_INV   0.0416666679f
#define QS   8192.0f
#define QSI  (1.0f / 8192.0f)
#define TBL_OFF_B 4128
#define TBL_BRICK_BYTES 1040000   // 25*25*13 bricks * 128B
#define VOLB_OFF_B 1044480        // 128B-aligned after table
#define VOL_N   (128 * 128 * 128)
#define WS_NEED ((size_t)VOLB_OFF_B + (size_t)VOL_N)

#define BUILD_BLOCKS 920      // 4 lanes per point-pair: 235300 thr / 256
#define CONV_BLOCKS  1024     // VOL_N / (256*8)

typedef float v2f __attribute__((ext_vector_type(2)));
typedef float f4  __attribute__((ext_vector_type(4)));
typedef unsigned u2 __attribute__((ext_vector_type(2)));
typedef unsigned u4 __attribute__((ext_vector_type(4)));
typedef short s4v __attribute__((ext_vector_type(4)));

__device__ __forceinline__ float bf2f(const __hip_bfloat16 v) {
    return __bfloat162float(v);
}
__device__ __forceinline__ v2f splat(float x) { v2f r; r.x = x; r.y = x; return r; }
__device__ __forceinline__ v2f vfma(v2f a, v2f b, v2f c) {
    return __builtin_elementwise_fma(a, b, c);
}
__device__ __forceinline__ float lerp1(float a, float b, float f) {
    return __builtin_fmaf(f, b - a, a);
}

// Vol brick address pieces: [bz:5][by:5][bx:4][z&3:2][y&3:2][x&7:3].
__device__ __forceinline__ int bpx(int x) { return ((x >> 3) << 7) | (x & 7); }
__device__ __forceinline__ int bpy(int y) { return ((y >> 2) << 11) | ((y & 3) << 3); }
__device__ __forceinline__ int bpz(int z) { return ((z >> 2) << 16) | ((z & 3) << 5); }

// Table brick addressing (8B entries; brick = 2 i0 x 2 i1 x 4 i2 = 16 entries
// = 128B; brick grid 25 x 25 x 13 row-major). Additive decomposition.
__device__ __forceinline__ int tf0(int i0) { return (i0 >> 1) * 5200 + (i0 & 1) * 8; }
__device__ __forceinline__ int tf1(int i1) { return (i1 >> 1) * 208 + (i1 & 1) * 4; }
__device__ __forceinline__ int tf2(int i2) { return (i2 >> 2) * 16 + (i2 & 3); }

__device__ __forceinline__ int detect_bf16(const void* p, int tid, int* sflag) {
    if (tid < 64) {
        unsigned e = (((const unsigned short*)p)[tid] >> 7) & 0xFFu;
        unsigned long long m = __ballot(e >= 97u && e <= 129u);
        if (tid == 0) *sflag = (__popcll(m) >= 52) ? 1 : 0;
    }
    __syncthreads();
    return *sflag;
}

// ---------------------------------------------------------------------------
// setup_kernel: FALLBACK-PATH ONLY (diffeo needs folded weights + flags in ws).
// ---------------------------------------------------------------------------
__global__ void setup_kernel(
    const void* __restrict__ coords,
    const void* __restrict__ W1_0, const void* __restrict__ b1_0,
    const void* __restrict__ W2_0, const void* __restrict__ b2_0,
    const void* __restrict__ W1_1, const void* __restrict__ b1_1,
    const void* __restrict__ W2_1, const void* __restrict__ b2_1,
    const void* __restrict__ vol,
    float* __restrict__ ws) {
    __shared__ int sflags[3];
    int tid = threadIdx.x;
    if (tid < 64) {
        auto sane = [](const void* p, int i) -> bool {
            unsigned e = (((const unsigned short*)p)[i] >> 7) & 0xFFu;
            return e >= 97u && e <= 129u;
        };
        unsigned long long m;
        m = __ballot(sane(W1_0, tid));
        if (tid == 0) sflags[2] = (__popcll(m) >= 52) ? 1 : 0;
        m = __ballot(sane(coords, tid));
        if (tid == 0) sflags[0] = (__popcll(m) >= 52) ? 1 : 0;
        m = __ballot(sane(vol, tid));
        if (tid == 0) sflags[1] = (__popcll(m) >= 52) ? 1 : 0;
    }
    __syncthreads();
    int isbf = sflags[2];
    const float K = 2.88539008177792681472f;  // 2/ln(2)
    int ode = tid >> 9;
    int r = tid & 511;
    const void* W1 = ode ? W1_1 : W1_0;
    const void* b1 = ode ? b1_1 : b1_0;
    const void* W2 = ode ? W2_1 : W2_0;
    const void* b2 = ode ? b2_1 : b2_0;
    auto ld = [&](const void* p, int idx) -> float {
        return isbf ? bf2f(((const __hip_bfloat16*)p)[idx]) : ((const float*)p)[idx];
    };
    float v = 0.0f;
    if (r < 192)       v = K * ld(W1, r);
    else if (r < 256)  v = K * ld(b1, r - 192);
    else if (r < 448)  v = -2.0f * ld(W2, r - 256);
    else if (r < 451) {
        int k = r - 448;
        float s = ld(b2, k);
        for (int j = 0; j < HID; ++j) s += ld(W2, 3 * j + k);
        v = s;
    }
    ws[(ode << 9) + r] = v;
    if (tid < 2) ((int*)(ws + 1024))[tid] = sflags[tid];
}

// Pair-point MLP (fallback path, lane-uniform weights from global ws).
__device__ __forceinline__ void mlp_f2(const float* __restrict__ w,
                                       v2f y0, v2f y1, v2f y2,
                                       v2f& o0, v2f& o1, v2f& o2) {
    v2f a0 = splat(w[448]), a1 = splat(w[449]), a2 = splat(w[450]);
#pragma unroll 8
    for (int j = 0; j < HID; ++j) {
        v2f pre = vfma(y0, splat(w[j]),
                  vfma(y1, splat(w[64 + j]),
                  vfma(y2, splat(w[128 + j]), splat(w[192 + j]))));
        v2f e;
        e.x = __builtin_amdgcn_exp2f(pre.x);
        e.y = __builtin_amdgcn_exp2f(pre.y);
        v2f q = e + splat(1.0f);
        float rP = __builtin_amdgcn_rcpf(q.x * q.y);
        v2f r;
        r.x = q.y * rP;
        r.y = q.x * rP;
        a0 = vfma(r, splat(w[256 + 3 * j + 0]), a0);
        a1 = vfma(r, splat(w[256 + 3 * j + 1]), a1);
        a2 = vfma(r, splat(w[256 + 3 * j + 2]), a2);
    }
    o0 = a0; o1 = a1; o2 = a2;
}

__device__ __forceinline__ void integrate2(const float* __restrict__ ws,
                                           v2f& y0, v2f& y1, v2f& y2) {
    const float h = H_EFF;
#pragma unroll 1
    for (int ode = 0; ode < 2; ++ode) {
        const float* __restrict__ w = ws + (ode << 9);
        v2f k0 = splat(0.f), k1 = splat(0.f), k2 = splat(0.f);
        v2f s0 = splat(0.f), s1 = splat(0.f), s2 = splat(0.f);
#pragma unroll 1
        for (int e = 0; e < 4; ++e) {
            float ae = (e == 0) ? 0.0f : ((e == 3) ? h : 0.5f * h);
            float we = (e == 1 || e == 2) ? 2.0f : 1.0f;
            v2f aev = splat(ae), wev = splat(we);
            v2f f0, f1, f2;
            mlp_f2(w, vfma(aev, k0, y0), vfma(aev, k1, y1), vfma(aev, k2, y2),
                   f0, f1, f2);
            k0 = f0; k1 = f1; k2 = f2;
            s0 = vfma(wev, k0, s0);
            s1 = vfma(wev, k1, s1);
            s2 = vfma(wev, k2, s2);
        }
        v2f h6 = splat(h / 6.0f);
        y0 = vfma(h6, s0, y0);
        y1 = vfma(h6, s1, y1);
        y2 = vfma(h6, s2, y2);
    }
}

// ---------------------------------------------------------------------------
// prep_kernel: fused build (blocks < BUILD_BLOCKS) + vol conversion (rest).
// Build: lane-QUAD per point-pair (v2f); lane h sums j in {h, h+4, ..., h+60}
// (stride-4 -> conflict-free LDS reads, R7 lesson); 2-step shfl_xor combine.
// ---------------------------------------------------------------------------
__global__ __launch_bounds__(256) void prep_kernel(
    const void* __restrict__ W1_0, const void* __restrict__ b1_0,
    const void* __restrict__ W2_0, const void* __restrict__ b2_0,
    const void* __restrict__ W1_1, const void* __restrict__ b1_1,
    const void* __restrict__ W2_1, const void* __restrict__ b2_1,
    const void* __restrict__ vol,
    float* __restrict__ ws) {
    int tid = threadIdx.x;
    if (blockIdx.x < BUILD_BLOCKS) {
        __shared__ int sflag;
        __shared__ f4 sw1[2][64];     // {K*W1[0][j], K*W1[1][j], K*W1[2][j], K*b1[j]}
        __shared__ f4 sw2[2][64];     // {-2*W2[j][0], -2*W2[j][1], -2*W2[j][2], 0}
        __shared__ float sb2[2][4];   // b2'' per ode
        int isbf = detect_bf16(W1_0, tid, &sflag);
        const float K = 2.88539008177792681472f;
        auto ld = [&](const void* p, int idx) -> float {
            return isbf ? bf2f(((const __hip_bfloat16*)p)[idx]) : ((const float*)p)[idx];
        };
        {
            int ode = (tid >> 6) & 1;
            int j = tid & 63;
            const void* W1 = ode ? W1_1 : W1_0;
            const void* b1 = ode ? b1_1 : b1_0;
            const void* W2 = ode ? W2_1 : W2_0;
            if (tid < 128) {
                f4 c = { K * ld(W1, j), K * ld(W1, 64 + j),
                         K * ld(W1, 128 + j), K * ld(b1, j) };
                sw1[ode][j] = c;
            } else {
                f4 c = { -2.f * ld(W2, 3 * j + 0), -2.f * ld(W2, 3 * j + 1),
                         -2.f * ld(W2, 3 * j + 2), 0.f };
                sw2[ode][j] = c;
            }
            if (tid < 6) {
                int o = tid / 3, k = tid - 3 * o;
                const void* W2o = o ? W2_1 : W2_0;
                const void* b2o = o ? b2_1 : b2_0;
                float s = ld(b2o, k);
                for (int jj = 0; jj < HID; ++jj) s += ld(W2o, 3 * jj + k);
                sb2[o][k] = s;
            }
        }
        __syncthreads();

        int gtid = blockIdx.x * 256 + tid;
        int lp = gtid >> 2;       // point-pair index
        int h  = gtid & 3;        // j-residue class (stride-4)
        int nA = 2 * lp;
        if (nA >= TB3) return;
        int nB = nA + 1;
        int nBc = nB < TB3 ? nB : (TB3 - 1);

        auto node_idx = [](int n, int* i0, int* i1, int* i2) {
            *i0 = n / TB2;
            int rem = n - *i0 * TB2;
            *i1 = rem / TB;
            *i2 = rem - *i1 * TB;
        };
        int iA0, iA1, iA2, iB0, iB1, iB2;
        node_idx(nA,  &iA0, &iA1, &iA2);
        node_idx(nBc, &iB0, &iB1, &iB2);
        v2f y0, y1, y2;
        y0.x = __builtin_fmaf((float)iA0, TB_INV, -1.0f);
        y1.x = __builtin_fmaf((float)iA1, TB_INV, -1.0f);
        y2.x = __builtin_fmaf((float)iA2, TB_INV, -1.0f);
        y0.y = __builtin_fmaf((float)iB0, TB_INV, -1.0f);
        y1.y = __builtin_fmaf((float)iB1, TB_INV, -1.0f);
        y2.y = __builtin_fmaf((float)iB2, TB_INV, -1.0f);

        const float hh = H_EFF;
#pragma unroll 1
        for (int ode = 0; ode < 2; ++ode) {
            const f4* __restrict__ w1 = sw1[ode];
            const f4* __restrict__ w2 = sw2[ode];
            v2f b2v0 = h ? splat(0.f) : splat(sb2[ode][0]);
            v2f b2v1 = h ? splat(0.f) : splat(sb2[ode][1]);
            v2f b2v2 = h ? splat(0.f) : splat(sb2[ode][2]);
            v2f k0 = splat(0.f), k1 = splat(0.f), k2 = splat(0.f);
            v2f s0 = splat(0.f), s1 = splat(0.f), s2 = splat(0.f);
#pragma unroll 1
            for (int e = 0; e < 4; ++e) {
                float ae = (e == 0) ? 0.0f : ((e == 3) ? hh : 0.5f * hh);
                float we = (e == 1 || e == 2) ? 2.0f : 1.0f;
                v2f aev = splat(ae), wev = splat(we);
                v2f z0 = vfma(aev, k0, y0);
                v2f z1 = vfma(aev, k1, y1);
                v2f z2 = vfma(aev, k2, y2);
                v2f a0 = b2v0, a1 = b2v1, a2 = b2v2;
#pragma unroll 8
                for (int jj = 0; jj < 16; ++jj) {
                    // stride-4: quad lanes read 16B-consecutive slots.
                    f4 c1 = w1[4 * jj + h];
                    v2f pre = vfma(z0, splat(c1.x),
                              vfma(z1, splat(c1.y),
                              vfma(z2, splat(c1.z), splat(c1.w))));
                    v2f ev;
                    ev.x = __builtin_amdgcn_exp2f(pre.x);
                    ev.y = __builtin_amdgcn_exp2f(pre.y);
                    v2f q = ev + splat(1.0f);
                    float rP = __builtin_amdgcn_rcpf(q.x * q.y);
                    v2f r;
                    r.x = q.y * rP;
                    r.y = q.x * rP;
                    f4 c2 = w2[4 * jj + h];
                    a0 = vfma(r, splat(c2.x), a0);
                    a1 = vfma(r, splat(c2.y), a1);
                    a2 = vfma(r, splat(c2.z), a2);
                }
                // combine 4 lane-quarters (commutative swaps -> bit-identical)
                v2f t;
                t.x = __shfl_xor(a0.x, 1); t.y = __shfl_xor(a0.y, 1); a0 += t;
                t.x = __shfl_xor(a1.x, 1); t.y = __shfl_xor(a1.y, 1); a1 += t;
                t.x = __shfl_xor(a2.x, 1); t.y = __shfl_xor(a2.y, 1); a2 += t;
                t.x = __shfl_xor(a0.x, 2); t.y = __shfl_xor(a0.y, 2); a0 += t;
                t.x = __shfl_xor(a1.x, 2); t.y = __shfl_xor(a1.y, 2); a1 += t;
                t.x = __shfl_xor(a2.x, 2); t.y = __shfl_xor(a2.y, 2); a2 += t;
                k0 = a0; k1 = a1; k2 = a2;
                s0 = vfma(wev, k0, s0);
                s1 = vfma(wev, k1, s1);
                s2 = vfma(wev, k2, s2);
            }
            v2f h6 = splat(hh / 6.0f);
            y0 = vfma(h6, s0, y0);
            y1 = vfma(h6, s1, y1);
            y2 = vfma(h6, s2, y2);
        }

        if (h == 0) {
            auto quant = [](float v) -> short {
                float q = v * QS;
                q = q < -32767.f ? -32767.f : (q > 32767.f ? 32767.f : q);
                return (short)(int)rintf(q);
            };
            s4v* T = (s4v*)((char*)ws + TBL_OFF_B);
            s4v qA = { quant(y0.x), quant(y1.x), quant(y2.x), 0 };
            T[tf0(iA0) + tf1(iA1) + tf2(iA2)] = qA;
            if (nB < TB3) {
                s4v qB = { quant(y0.y), quant(y1.y), quant(y2.y), 0 };
                T[tf0(iB0) + tf1(iB1) + tf2(iB2)] = qB;
            }
        }
    } else {
        // ------- conv: quantize vol to u8 in 128B-brick layout, 8 vox/thread
        __shared__ int svf;
        int vbf = detect_bf16(vol, tid, &svf);
        int g = (blockIdx.x - BUILD_BLOCKS) * 256 + tid;
        int d0 = g * 8;                        // 8 consecutive bricked bytes
        int x0 = ((d0 >> 7) & 15) << 3;        // d0&7 == 0
        int yy = (((d0 >> 11) & 31) << 2) | ((d0 >> 3) & 3);
        int zz = (((d0 >> 16) & 31) << 2) | ((d0 >> 5) & 3);
        int src = (zz << 14) | (yy << 7) | x0; // 8 consecutive source voxels
        float v[8];
        if (vbf) {
            u4 w = *(const u4*)((const unsigned short*)vol + src);
#pragma unroll
            for (int i = 0; i < 4; ++i) {
                unsigned ww = w[i];
                v[2 * i + 0] = __builtin_bit_cast(float, ww << 16);
                v[2 * i + 1] = __builtin_bit_cast(float, ww & 0xFFFF0000u);
            }
        } else {
            const f4* F = (const f4*)((const float*)vol + src);
            f4 A = F[0], B = F[1];
            v[0] = A.x; v[1] = A.y; v[2] = A.z; v[3] = A.w;
            v[4] = B.x; v[5] = B.y; v[6] = B.z; v[7] = B.w;
        }
        unsigned q[8];
#pragma unroll
        for (int i = 0; i < 8; ++i) {
            float qq = __builtin_fmaf(v[i], 255.0f, 0.5f);
            qq = qq < 0.f ? 0.f : (qq > 255.f ? 255.f : qq);
            q[i] = (unsigned)qq;
        }
        u2 pk;
        pk.x = q[0] | (q[1] << 8) | (q[2] << 16) | (q[3] << 24);
        pk.y = q[4] | (q[5] << 8) | (q[6] << 16) | (q[7] << 24);
        *(u2*)((unsigned char*)ws + VOLB_OFF_B + d0) = pk;
    }
}

// fp-source grid-sample for the fallback path.
__device__ __forceinline__ float sample3d(const void* __restrict__ vol, int vbf,
                                          float cz, float cy, float cx) {
    float fx = (cx + 1.0f) * 64.0f - 0.5f;
    float fy = (cy + 1.0f) * 64.0f - 0.5f;
    float fz = (cz + 1.0f) * 64.0f - 0.5f;
    float x0f = floorf(fx), y0f = floorf(fy), z0f = floorf(fz);
    float tx = fx - x0f, ty = fy - y0f, tz = fz - z0f;
    int x0 = (int)x0f, y0 = (int)y0f, z0 = (int)z0f;
    int x1 = x0 + 1, y1 = y0 + 1, z1 = z0 + 1;
    auto clampi = [](int v) { return v < 0 ? 0 : (v > 127 ? 127 : v); };
    auto valid = [](int zi, int yi, int xi) -> bool {
        return ((unsigned)zi < 128u) && ((unsigned)yi < 128u) && ((unsigned)xi < 128u);
    };
    int xc0 = clampi(x0), xc1 = clampi(x1);
    int yc0 = clampi(y0), yc1 = clampi(y1);
    int zc0 = clampi(z0), zc1 = clampi(z1);
    int idx[8] = {
        (zc0 << 14) | (yc0 << 7) | xc0, (zc0 << 14) | (yc0 << 7) | xc1,
        (zc0 << 14) | (yc1 << 7) | xc0, (zc0 << 14) | (yc1 << 7) | xc1,
        (zc1 << 14) | (yc0 << 7) | xc0, (zc1 << 14) | (yc0 << 7) | xc1,
        (zc1 << 14) | (yc1 << 7) | xc0, (zc1 << 14) | (yc1 << 7) | xc1 };
    float v[8];
    if (vbf) {
        const __hip_bfloat16* V = (const __hip_bfloat16*)vol;
#pragma unroll
        for (int q = 0; q < 8; ++q) v[q] = bf2f(V[idx[q]]);
    } else {
        const float* V = (const float*)vol;
#pragma unroll
        for (int q = 0; q < 8; ++q) v[q] = V[idx[q]];
    }
    if (!valid(z0, y0, x0)) v[0] = 0.f;
    if (!valid(z0, y0, x1)) v[1] = 0.f;
    if (!valid(z0, y1, x0)) v[2] = 0.f;
    if (!valid(z0, y1, x1)) v[3] = 0.f;
    if (!valid(z1, y0, x0)) v[4] = 0.f;
    if (!valid(z1, y0, x1)) v[5] = 0.f;
    if (!valid(z1, y1, x0)) v[6] = 0.f;
    if (!valid(z1, y1, x1)) v[7] = 0.f;
    return v[0] * (1.f - tz) * (1.f - ty) * (1.f - tx) +
           v[1] * (1.f - tz) * (1.f - ty) * tx +
           v[2] * (1.f - tz) * ty * (1.f - tx) +
           v[3] * (1.f - tz) * ty * tx +
           v[4] * tz * (1.f - ty) * (1.f - tx) +
           v[5] * tz * (1.f - ty) * tx +
           v[6] * tz * ty * (1.f - tx) +
           v[7] * tz * ty * tx;
}

// ---------------------------------------------------------------------------
// Query: 1 pt/thread, 3456 blocks (100% occ cap). Bricked table + vol,
// per-point FP ops identical to R8/R9 -> absmax unchanged.
// ---------------------------------------------------------------------------
__global__ __launch_bounds__(256) void query_kernel(
    const void* __restrict__ coords,
    const float* __restrict__ ws,
    float* __restrict__ out) {
    __shared__ int scf;
    int cbf = detect_bf16(coords, threadIdx.x, &scf);
    int i = blockIdx.x * 256 + threadIdx.x;   // point index
    if (i >= NPTS) return;

    float y0, y1, y2;
    if (cbf) {
        const unsigned short* C = (const unsigned short*)coords + 3 * i;
        y0 = __builtin_bit_cast(float, (unsigned)C[0] << 16);
        y1 = __builtin_bit_cast(float, (unsigned)C[1] << 16);
        y2 = __builtin_bit_cast(float, (unsigned)C[2] << 16);
    } else {
        const float* C = (const float*)coords + 3 * i;
        y0 = C[0]; y1 = C[1]; y2 = C[2];
    }

    auto cell = [](float tt, int* idx, float* f) {
        int v = (int)floorf(tt);
        v = v < 0 ? 0 : (v > TB - 2 ? TB - 2 : v);
        *idx = v; *f = tt - (float)v;
    };

    int i0, i1, i2;
    float f0, f1, f2;
    cell((y0 + 1.0f) * TB_SCALE, &i0, &f0);
    cell((y1 + 1.0f) * TB_SCALE, &i1, &f1);
    cell((y2 + 1.0f) * TB_SCALE, &i2, &f2);

    const s4v* T = (const s4v*)((const char*)ws + TBL_OFF_B);
    int a0 = tf0(i0), a0b = tf0(i0 + 1);
    int a1 = tf1(i1), a1b = tf1(i1 + 1);
    int a2 = tf2(i2), a2b = tf2(i2 + 1);
    s4v e000 = T[a0 + a1 + a2];
    s4v e001 = T[a0 + a1 + a2b];
    s4v e010 = T[a0 + a1b + a2];
    s4v e011 = T[a0 + a1b + a2b];
    s4v e100 = T[a0b + a1 + a2];
    s4v e101 = T[a0b + a1 + a2b];
    s4v e110 = T[a0b + a1b + a2];
    s4v e111 = T[a0b + a1b + a2b];

    float c1v[3];
#pragma unroll
    for (int d = 0; d < 3; ++d) {
        float a00 = lerp1((float)e000[d], (float)e001[d], f2);
        float a01 = lerp1((float)e010[d], (float)e011[d], f2);
        float a10 = lerp1((float)e100[d], (float)e101[d], f2);
        float a11 = lerp1((float)e110[d], (float)e111[d], f2);
        c1v[d] = lerp1(lerp1(a00, a01, f1), lerp1(a10, a11, f1), f0) * QSI;
    }

    // c1 out: 3 contiguous floats (coalesced dword stores across the wave).
    {
        float* dst = out + NPTS + 3 * i;
        dst[0] = c1v[0];
        dst[1] = c1v[1];
        dst[2] = c1v[2];
    }

    const unsigned char* VB = (const unsigned char*)ws + VOLB_OFF_B;
    {
        float fx = (c1v[2] + 1.0f) * 64.0f - 0.5f;
        float fy = (c1v[1] + 1.0f) * 64.0f - 0.5f;
        float fz = (c1v[0] + 1.0f) * 64.0f - 0.5f;
        float x0f = floorf(fx), y0f = floorf(fy), z0f = floorf(fz);
        float tx = fx - x0f, ty = fy - y0f, tz = fz - z0f;
        int x0 = (int)x0f, y0i = (int)y0f, z0 = (int)z0f;
        int x1 = x0 + 1, y1i = y0i + 1, z1 = z0 + 1;
        auto clampi = [](int v) { return v < 0 ? 0 : (v > 127 ? 127 : v); };
        auto valid = [](int zi, int yi, int xi) -> bool {
            return ((unsigned)zi < 128u) && ((unsigned)yi < 128u) &&
                   ((unsigned)xi < 128u);
        };
        int px0 = bpx(clampi(x0)), px1 = bpx(clampi(x1));
        int py0 = bpy(clampi(y0i)), py1 = bpy(clampi(y1i));
        int pz0 = bpz(clampi(z0)), pz1 = bpz(clampi(z1));
        float v[8];
        v[0] = (float)VB[pz0 | py0 | px0];
        v[1] = (float)VB[pz0 | py0 | px1];
        v[2] = (float)VB[pz0 | py1 | px0];
        v[3] = (float)VB[pz0 | py1 | px1];
        v[4] = (float)VB[pz1 | py0 | px0];
        v[5] = (float)VB[pz1 | py0 | px1];
        v[6] = (float)VB[pz1 | py1 | px0];
        v[7] = (float)VB[pz1 | py1 | px1];
        if (!valid(z0, y0i, x0)) v[0] = 0.f;
        if (!valid(z0, y0i, x1)) v[1] = 0.f;
        if (!valid(z0, y1i, x0)) v[2] = 0.f;
        if (!valid(z0, y1i, x1)) v[3] = 0.f;
        if (!valid(z1, y0i, x0)) v[4] = 0.f;
        if (!valid(z1, y0i, x1)) v[5] = 0.f;
        if (!valid(z1, y1i, x0)) v[6] = 0.f;
        if (!valid(z1, y1i, x1)) v[7] = 0.f;
        float sraw =
            v[0] * (1.f - tz) * (1.f - ty) * (1.f - tx) +
            v[1] * (1.f - tz) * (1.f - ty) * tx +
            v[2] * (1.f - tz) * ty * (1.f - tx) +
            v[3] * (1.f - tz) * ty * tx +
            v[4] * tz * (1.f - ty) * (1.f - tx) +
            v[5] * tz * (1.f - ty) * tx +
            v[6] * tz * ty * (1.f - tx) +
            v[7] * tz * ty * tx;
        out[i] = __builtin_fmaf(sraw, 2.0f / 255.0f, -1.0f);
    }
}

// Fallback direct kernel (2 pts/thread) for small ws_size.
__global__ __launch_bounds__(64) void diffeo_kernel(
    const void* __restrict__ coords,
    const float* __restrict__ ws,
    const void* __restrict__ vol,
    float* __restrict__ out) {
    int t = blockIdx.x * 64 + threadIdx.x;   // pair index
    if (t >= NPTS / 2) return;

    const int* flags = (const int*)(ws + 1024);
    int cbf = flags[0];
    int vbf = flags[1];

    v2f y0, y1, y2;
    if (cbf) {
        const __hip_bfloat16* C = (const __hip_bfloat16*)coords;
        int b = 6 * t;
        y0.x = bf2f(C[b + 0]); y1.x = bf2f(C[b + 1]); y2.x = bf2f(C[b + 2]);
        y0.y = bf2f(C[b + 3]); y1.y = bf2f(C[b + 4]); y2.y = bf2f(C[b + 5]);
    } else {
        const float* C = (const float*)coords;
        int b = 6 * t;
        y0.x = C[b + 0]; y1.x = C[b + 1]; y2.x = C[b + 2];
        y0.y = C[b + 3]; y1.y = C[b + 4]; y2.y = C[b + 5];
    }

    integrate2(ws, y0, y1, y2);

    int b = 6 * t;
    out[NPTS + b + 0] = y0.x; out[NPTS + b + 1] = y1.x; out[NPTS + b + 2] = y2.x;
    out[NPTS + b + 3] = y0.y; out[NPTS + b + 4] = y1.y; out[NPTS + b + 5] = y2.y;

    float sA = sample3d(vol, vbf, y0.x, y1.x, y2.x);
    float sB = sample3d(vol, vbf, y0.y, y1.y, y2.y);
    out[2 * t + 0] = __builtin_fmaf(2.0f, sA, -1.0f);
    out[2 * t + 1] = __builtin_fmaf(2.0f, sB, -1.0f);
}

extern "C" void kernel_launch(void* const* d_in, const int* in_sizes, int n_in,
                              void* d_out, int out_size, void* d_ws, size_t ws_size,
                              hipStream_t stream) {
    const void* coords = d_in[0];
    const void* W1_0 = d_in[1];
    const void* b1_0 = d_in[2];
    const void* W2_0 = d_in[3];
    const void* b2_0 = d_in[4];
    const void* W1_1 = d_in[5];
    const void* b1_1 = d_in[6];
    const void* W2_1 = d_in[7];
    const void* b2_1 = d_in[8];
    const void* vol  = d_in[9];
    float* out = (float*)d_out;
    float* ws = (float*)d_ws;

    if (ws_size >= WS_NEED) {
        prep_kernel<<<BUILD_BLOCKS + CONV_BLOCKS, 256, 0, stream>>>(
            W1_0, b1_0, W2_0, b2_0, W1_1, b1_1, W2_1, b2_1, vol, ws);
        query_kernel<<<NPTS / 256, 256, 0, stream>>>(coords, ws, out);
    } else {
        setup_kernel<<<1, 1024, 0, stream>>>(coords, W1_0, b1_0, W2_0, b2_0,
                                             W1_1, b1_1, W2_1, b2_1, vol, ws);
        diffeo_kernel<<<(NPTS / 2) / 64, 64, 0, stream>>>(coords, ws, vol, out);
    }
}